// Round 17
// baseline (297.431 us; speedup 1.0000x reference)
//
#include <hip/hip_runtime.h>
#include <cstdint>

#define BB 256
#define SS 2048
#define TT 64
#define LOG64 4.158883083359672

// ---------------- ws layout (float offsets) ----------------
#define OUTB 0
#define GBASE 256
#define LBASE 512
#define LSIZE (256 * 16 * 64)           // per-column log scales (max nseg=16)
#define PBASE_F (LBASE + LSIZE)         // 262656 floats (~1.05 MB)
// P stored as bf16: (BB*nseg) matrices x 4096 entries

// ---------------- old-path (R7 fallback) constants ----------------
#define M_SPLIT 1024
#define WS_STRIDE 144

typedef float  f32x16 __attribute__((ext_vector_type(16)));
typedef float  f32x4v __attribute__((ext_vector_type(4)));
typedef unsigned int u32x4 __attribute__((ext_vector_type(4)));
typedef int    i32x2v __attribute__((ext_vector_type(2)));
typedef __bf16 bf16x8 __attribute__((ext_vector_type(8)));

__device__ __forceinline__ int ldtag(const uint32_t* tw, int i, int is64) {
    return (int)tw[i << is64];
}

__device__ __forceinline__ unsigned cvt_pk_bf16(float lo, float hi) {
    unsigned r;
    asm("v_cvt_pk_bf16_f32 %0, %1, %2" : "=v"(r) : "v"(lo), "v"(hi));
    return r;
}

// device-pass-only builtin selection; host pass sees the asm branch (never codegen'd)
__device__ __forceinline__ f32x16 mfma32(u32x4 a, u32x4 b, f32x16 c) {
#if __has_builtin(__builtin_amdgcn_mfma_f32_32x32x16_bf16)
    return __builtin_amdgcn_mfma_f32_32x32x16_bf16(
        __builtin_bit_cast(bf16x8, a), __builtin_bit_cast(bf16x8, b), c, 0, 0, 0);
#else
    f32x16 d;
    asm volatile("v_mfma_f32_32x32x16_bf16 %0, %1, %2, %3\n\ts_nop 7\n\ts_nop 7"
        : "=v"(d) : "v"(a), "v"(b), "v"(c));
    return d;
#endif
}

// two-output half-wave swap: a' = {a.lo, b.lo}, b' = {a.hi, b.hi}
__device__ __forceinline__ void plswap(unsigned& a, unsigned& b, bool hb) {
#if __has_builtin(__builtin_amdgcn_permlane32_swap)
    (void)hb;
    i32x2v r = __builtin_amdgcn_permlane32_swap((int)a, (int)b, false, false);
    a = (unsigned)r[0]; b = (unsigned)r[1];
#else
    const unsigned xa = __shfl_xor(a, 32);
    const unsigned xb = __shfl_xor(b, 32);
    const unsigned na = hb ? xb : a;
    const unsigned nb = hb ? b : xa;
    a = na; b = nb;
#endif
}

// ---------------- gold score body (used fused into seg grid + standalone) -------
__device__ __forceinline__ void gold_body(
    const float* __restrict__ em, const float* __restrict__ trans,
    const uint32_t* __restrict__ tw, float* __restrict__ gdst, int gstride,
    int b, int tid)
{
    uint32_t orv = 0;
    for (int k = 1; k < 32; k += 2) orv |= tw[k];
    const int is64 = (orv == 0) ? 1 : 0;
    const int    tbase = b * SS;
    const size_t ebase = (size_t)b * SS * TT;
    float s = 0.0f;
    for (int t = tid; t < SS; t += 256) {
        const int tg = ldtag(tw, tbase + t, is64);
        float v = em[ebase + (size_t)t * TT + tg];
        if (t > 0) {
            const int tp = ldtag(tw, tbase + t - 1, is64);
            v += trans[tp * TT + tg];
        }
        s += v;
    }
    for (int off = 1; off < 64; off <<= 1) s += __shfl_xor(s, off);
    __shared__ float sh[4];
    if ((tid & 63) == 0) sh[tid >> 6] = s;
    __syncthreads();
    if (tid == 0) gdst[b * gstride] = sh[0] + sh[1] + sh[2] + sh[3];
}

// ================= segment matrix-product kernel (32x32x16) =================
// 4 INDEPENDENT waves per 256-thread block. R17 change vs R16: the per-step
// column-tile accumulation is split into TWO independent 2-deep MFMA chains
// (c0a,c0b) joined in the f-scale: c0 = (c0a+c0b) .* f  (pk_add+pk_mul).
// R16's 4-dep-MFMA chain (~200cyc latency) was the 51%-MfmaUtil wall; 4
// independent chains/wave feed the matrix pipe continuously.
// __launch_bounds__(256,3): acc regs 32->64, total ~150 needs the 170 budget
// (R14 lesson: never under-budget; (256,8)'s 32-VGPR cap caused a 4.5x spill
// catastrophe).
// Wave u = blockIdx.x*4+wv -> (bs = u>>1, strip w = u&1); private f_lds slice;
// f double-buffered (write si+1's f during si). Gold fused as trailing blocks.
// Layouts (32x32x16 bf16): A row=l&31,k=(l>>5)*8+e ; B col=l&31,k=(l>>5)*8+e ;
// C col=l&31,row=(r&3)+8*(r>>2)+4*(l>>5)  [HW-verified; R12/R13/R15/R16 absmax=0].
__global__ __launch_bounds__(256, 3) void crf_seg32_kernel(
    const float* __restrict__ em, const float* __restrict__ trans,
    const uint32_t* __restrict__ tw,
    float* __restrict__ ws, int sshift, int nsb)
{
    const int tid = threadIdx.x;

    if ((int)blockIdx.x >= nsb) {              // trailing blocks: gold score
        gold_body(em, trans, tw, ws + GBASE, 1, (int)blockIdx.x - nsb, tid);
        return;
    }

    const int wv = tid >> 6;                   // wave in block
    const int l  = tid & 63;
    const int c = l & 31, h = l >> 5;
    const bool hb = (h != 0);
    const int u  = blockIdx.x * 4 + wv;        // global wave id
    const int bs = u >> 1;                     // b*nseg + s
    const int w  = u & 1;                      // strip
    const int b  = bs >> sshift;
    const int s  = bs & ((1 << sshift) - 1);
    const int cn = w * 32 + c;                 // global column of this lane
    __shared__ __align__(16) float f_lds[4][2][TT];   // [wave][slot][state]
    float* fl = &f_lds[wv][0][0];

    const f32x16 ZZ = {0,0,0,0,0,0,0,0,0,0,0,0,0,0,0,0};

    // A tiles (E^T): A[m][k], m = 32mt + c, k = 16kt + 8h + e
#define MKA(NM, mt, kt) u32x4 NM; { \
        const int kb = 16*(kt) + 8*h; const int mc = 32*(mt) + c; \
        const float e0 = __expf(trans[(kb+0)*64 + mc]) * 0.015625f; \
        const float e1 = __expf(trans[(kb+1)*64 + mc]) * 0.015625f; \
        const float e2 = __expf(trans[(kb+2)*64 + mc]) * 0.015625f; \
        const float e3 = __expf(trans[(kb+3)*64 + mc]) * 0.015625f; \
        const float e4 = __expf(trans[(kb+4)*64 + mc]) * 0.015625f; \
        const float e5 = __expf(trans[(kb+5)*64 + mc]) * 0.015625f; \
        const float e6 = __expf(trans[(kb+6)*64 + mc]) * 0.015625f; \
        const float e7 = __expf(trans[(kb+7)*64 + mc]) * 0.015625f; \
        NM[0] = cvt_pk_bf16(e0, e1); NM[1] = cvt_pk_bf16(e2, e3); \
        NM[2] = cvt_pk_bf16(e4, e5); NM[3] = cvt_pk_bf16(e6, e7); }
    MKA(A00, 0, 0) MKA(A01, 0, 1) MKA(A02, 0, 2) MKA(A03, 0, 3)
    MKA(A10, 1, 0) MKA(A11, 1, 1) MKA(A12, 1, 2) MKA(A13, 1, 3)
#undef MKA

    // B init: identity strip. B[k][cn] = (k == cn), k = 16kt + 8h + e
#define MKB(NM, kt) u32x4 NM; { \
        const int kb = 16*(kt) + 8*h; \
        NM[0] = cvt_pk_bf16(kb+0==cn?1.f:0.f, kb+1==cn?1.f:0.f); \
        NM[1] = cvt_pk_bf16(kb+2==cn?1.f:0.f, kb+3==cn?1.f:0.f); \
        NM[2] = cvt_pk_bf16(kb+4==cn?1.f:0.f, kb+5==cn?1.f:0.f); \
        NM[3] = cvt_pk_bf16(kb+6==cn?1.f:0.f, kb+7==cn?1.f:0.f); }
    MKB(B0, 0) MKB(B1, 1) MKB(B2, 2) MKB(B3, 3)
#undef MKB

    const size_t ebase = (size_t)b * (SS * TT);
    const int nseg = 1 << sshift;
    const int L  = SS >> sshift;
    const int t0 = s * L + 1;
    const int t1 = (s == nseg - 1) ? (SS - 1) : (s + 1) * L;
    const int nst = t1 - t0 + 1;

    // depth-8 emission prefetch (t0+7 <= SS-1 for all segments, L>=128)
    float p0 = em[ebase + (size_t)(t0 + 0) * TT + l];
    float p1 = em[ebase + (size_t)(t0 + 1) * TT + l];
    float p2 = em[ebase + (size_t)(t0 + 2) * TT + l];
    float p3 = em[ebase + (size_t)(t0 + 3) * TT + l];
    float p4 = em[ebase + (size_t)(t0 + 4) * TT + l];
    float p5 = em[ebase + (size_t)(t0 + 5) * TT + l];
    float p6 = em[ebase + (size_t)(t0 + 6) * TT + l];
    float p7 = em[ebase + (size_t)(t0 + 7) * TT + l];

    float logacc = 0.f;
    f32x16 c0, c1;
    int si = 0;

    fl[0 * TT + l] = __expf(p0);               // f for step 0 (slot 0)

    // join+scale: C = (Ca + Cb) .* f   (compiler packs to v_pk_add/v_pk_mul)
#define JSC(C_, Ca_, Cb_, q, FV) { \
        C_[4*(q)+0] = (Ca_[4*(q)+0] + Cb_[4*(q)+0]) * FV[0]; \
        C_[4*(q)+1] = (Ca_[4*(q)+1] + Cb_[4*(q)+1]) * FV[1]; \
        C_[4*(q)+2] = (Ca_[4*(q)+2] + Cb_[4*(q)+2]) * FV[2]; \
        C_[4*(q)+3] = (Ca_[4*(q)+3] + Cb_[4*(q)+3]) * FV[3]; }
#define MX(v) mx = fmaxf(mx, v);
#define FEED(Bd, C_, o) { \
        unsigned T0 = cvt_pk_bf16(C_[(o)+0], C_[(o)+1]); \
        unsigned T1 = cvt_pk_bf16(C_[(o)+2], C_[(o)+3]); \
        unsigned T2 = cvt_pk_bf16(C_[(o)+4], C_[(o)+5]); \
        unsigned T3 = cvt_pk_bf16(C_[(o)+6], C_[(o)+7]); \
        plswap(T0, T2, hb); plswap(T1, T3, hb); \
        Bd[0] = T0; Bd[1] = T1; Bd[2] = T2; Bd[3] = T3; }

    // one step; KPAR = si&1 (compile-time in unrolled body), DOREN = renorm flag
#define STEPB(KPAR, DOREN) { \
        const float frn = __expf(p1); \
        fl[(((KPAR)+1)&1) * TT + l] = frn;     /* f for step si+1, other slot */ \
        p0=p1; p1=p2; p2=p3; p3=p4; p4=p5; p5=p6; p6=p7; \
        { int tp = t0 + si + 8; if (tp > SS-1) tp = SS-1; \
          p7 = em[ebase + (size_t)tp * TT + l]; } \
        /* 4 INDEPENDENT 2-deep MFMA chains (halved dep depth vs R16) */ \
        f32x16 c0a = mfma32(A00, B0, ZZ);  f32x16 c1a = mfma32(A10, B0, ZZ); \
        f32x16 c0b = mfma32(A02, B2, ZZ);  f32x16 c1b = mfma32(A12, B2, ZZ); \
        c0a = mfma32(A01, B1, c0a);        c1a = mfma32(A11, B1, c1a); \
        c0b = mfma32(A03, B3, c0b);        c1b = mfma32(A13, B3, c1b); \
        const float* flr = fl + ((KPAR)&1) * TT; \
        const f32x4v f0 = *(const f32x4v*)(flr +  0 + 4*h); \
        const f32x4v f1 = *(const f32x4v*)(flr +  8 + 4*h); \
        const f32x4v f2 = *(const f32x4v*)(flr + 16 + 4*h); \
        const f32x4v f3 = *(const f32x4v*)(flr + 24 + 4*h); \
        const f32x4v f4 = *(const f32x4v*)(flr + 32 + 4*h); \
        const f32x4v f5 = *(const f32x4v*)(flr + 40 + 4*h); \
        const f32x4v f6 = *(const f32x4v*)(flr + 48 + 4*h); \
        const f32x4v f7 = *(const f32x4v*)(flr + 56 + 4*h); \
        JSC(c0, c0a, c0b, 0, f0) JSC(c0, c0a, c0b, 1, f1) \
        JSC(c0, c0a, c0b, 2, f2) JSC(c0, c0a, c0b, 3, f3) \
        JSC(c1, c1a, c1b, 0, f4) JSC(c1, c1a, c1b, 1, f5) \
        JSC(c1, c1a, c1b, 2, f6) JSC(c1, c1a, c1b, 3, f7) \
        if (DOREN) { \
            float mx = c0[0]; \
            MX(c0[1]) MX(c0[2]) MX(c0[3]) MX(c0[4]) MX(c0[5]) MX(c0[6]) MX(c0[7]) \
            MX(c0[8]) MX(c0[9]) MX(c0[10]) MX(c0[11]) MX(c0[12]) MX(c0[13]) MX(c0[14]) MX(c0[15]) \
            MX(c1[0]) MX(c1[1]) MX(c1[2]) MX(c1[3]) MX(c1[4]) MX(c1[5]) MX(c1[6]) MX(c1[7]) \
            MX(c1[8]) MX(c1[9]) MX(c1[10]) MX(c1[11]) MX(c1[12]) MX(c1[13]) MX(c1[14]) MX(c1[15]) \
            mx = fmaxf(mx, __shfl_xor(mx, 32)); \
            const float inv = __builtin_amdgcn_rcpf(mx); \
            c0 *= inv; c1 *= inv; \
            logacc += __logf(mx); \
        } \
        FEED(B0, c0, 0) FEED(B1, c0, 8) FEED(B2, c1, 0) FEED(B3, c1, 8) \
        ++si; }

    const int nouter = nst >> 3;
    for (int o = 0; o < nouter; ++o) {
        STEPB(0, false) STEPB(1, false) STEPB(0, false) STEPB(1, false)
        STEPB(0, false) STEPB(1, false) STEPB(0, false) STEPB(1, true)
    }
    // tail (nst%8 < 8 steps; si&7 never reaches 7 here, so no renorm)
    for (; si < nst; ) {
        const int kp = si & 1;
        if (kp == 0) { STEPB(0, false) } else { STEPB(1, false) }
    }
#undef STEPB
#undef FEED
#undef MX
#undef JSC

    // store P^T[cn][row] as bf16; rows: quad q of tile mt -> 32mt + 8q + 4h + {0..3}
    uint16_t* ptu = (uint16_t*)(ws + PBASE_F)
                  + (size_t)bs * 4096 + (size_t)cn * 64;
#define STQ(C_, q, base) { \
        *(unsigned*)(ptu + (base) + 8*(q) + 4*h)     = cvt_pk_bf16(C_[4*(q)+0], C_[4*(q)+1]); \
        *(unsigned*)(ptu + (base) + 8*(q) + 4*h + 2) = cvt_pk_bf16(C_[4*(q)+2], C_[4*(q)+3]); }
    STQ(c0,0,0) STQ(c0,1,0) STQ(c0,2,0) STQ(c0,3,0)
    STQ(c1,0,32) STQ(c1,1,32) STQ(c1,2,32) STQ(c1,3,32)
#undef STQ
    if (h == 0)
        ws[LBASE + bs * 64 + cn] = logacc + (float)((double)nst * LOG64);
}

// ================= combine: alpha <- P_s alpha over segments =================
__global__ __launch_bounds__(64) void crf_combine2(
    const float* __restrict__ em, float* __restrict__ ws, int sshift)
{
    const int b = blockIdx.x, m = threadIdx.x;
    const int nseg = 1 << sshift;
    __shared__ float xs[TT];
    float alpha = __expf(em[(size_t)b * (SS * TT) + m]);   // alpha_0
    float logA = 0.f;
    for (int s = 0; s < nseg; ++s) {
        const int seg = b * nseg + s;
        const float Li = ws[LBASE + seg * 64 + m];         // per-column scale
        float Lmax = Li;
        for (int off = 1; off < 64; off <<= 1) Lmax = fmaxf(Lmax, __shfl_xor(Lmax, off));
        xs[m] = alpha * __expf(Li - Lmax);
        const uint16_t* Pp = (const uint16_t*)(ws + PBASE_F) + (size_t)seg * 4096;
        float y = 0.f;
#pragma unroll 8
        for (int i = 0; i < TT; ++i) {
            const float pv = __uint_as_float((unsigned)Pp[i * 64 + m] << 16);
            y = fmaf(pv, xs[i], y);
        }
        logA += Lmax;
        float mx = y;
        for (int off = 1; off < 64; off <<= 1) mx = fmaxf(mx, __shfl_xor(mx, off));
        alpha = y * __builtin_amdgcn_rcpf(mx);
        logA += __logf(mx);
    }
    float ssum = alpha;
    for (int off = 1; off < 64; off <<= 1) ssum += __shfl_xor(ssum, off);
    if (m == 0)
        ws[OUTB + b] = ws[GBASE + b] - (logA + __logf(ssum));   // gold - logZ
}

// ================= standalone gold (R7 fallback path) =================
__global__ __launch_bounds__(256) void crf_gold_kernel(
    const float* __restrict__ em, const float* __restrict__ trans,
    const uint32_t* __restrict__ tw, float* __restrict__ gdst, int gstride)
{
    gold_body(em, trans, tw, gdst, gstride, blockIdx.x, threadIdx.x);
}

// ================= old path (R7, proven fallback) =================
__device__ __forceinline__ float qsum4(float v) {
    int a = __builtin_amdgcn_mov_dpp(__float_as_int(v), 0xB1, 0xF, 0xF, true);
    float v1 = v + __int_as_float(a);
    int b2 = __builtin_amdgcn_mov_dpp(__float_as_int(v1), 0x4E, 0xF, 0xF, true);
    return v1 + __int_as_float(b2);
}
#define LDS_BARRIER() asm volatile("s_waitcnt lgkmcnt(0)\n\ts_barrier" ::: "memory")

template <int DIR>
__device__ __forceinline__ void fb_run(const float* __restrict__ em,
                                       const float* __restrict__ trans,
                                       float* __restrict__ ws,
                                       float* __restrict__ qbuf,
                                       int b, int tid)
{
    const int l   = tid & 63;
    const int w   = tid >> 6;
    const int j   = (w << 4) | (l >> 2);
    const int sub = l & 3;
#define TRIDX(k) (DIR ? (j * 64 + (sub * 16 + (k))) : ((sub * 16 + (k)) * 64 + j))
#define ED(k) const float E##k = __expf(trans[TRIDX(k)]) * 0.015625f;
    ED(0) ED(1) ED(2) ED(3) ED(4) ED(5) ED(6) ED(7)
    ED(8) ED(9) ED(10) ED(11) ED(12) ED(13) ED(14) ED(15)
#undef ED
#undef TRIDX
    const size_t ebase  = (size_t)b * SS * TT;
    constexpr int nsteps = DIR ? (SS - M_SPLIT) : (M_SPLIT - 1);
    constexpr int estep  = DIR ? -TT : TT;
    constexpr int t0     = DIR ? (SS - 2) : 1;
    const float* ep = em + ebase + (size_t)t0 * TT + j;
    float p0 = ep[0];
    float p1 = ep[1 * estep];
    float p2 = ep[2 * estep];
    float p3 = ep[3 * estep];
    if (tid < TT) {
        const size_t it = DIR ? ((size_t)(SS - 1) * TT) : 0;
        qbuf[tid] = __expf(em[ebase + it + tid]);
    }
    LDS_BARRIER();
    float logsum = 0.0f;
    int cur = 0;
    for (int si = 0; si < nsteps; ++si) {
        const float e = p0;
        p0 = p1; p1 = p2; p2 = p3;
        p3 = ep[4 * estep];
        ep += estep;
        float* rb = qbuf + (cur << 6);
        float* wb = qbuf + ((cur ^ 1) << 6);
        const float4 q0 = *(const float4*)(rb + sub * 16 + 0);
        const float4 q1 = *(const float4*)(rb + sub * 16 + 4);
        const float4 q2 = *(const float4*)(rb + sub * 16 + 8);
        const float4 q3 = *(const float4*)(rb + sub * 16 + 12);
        float a0 = 0, a1 = 0, a2 = 0, a3 = 0;
        a0 = fmaf(q0.x, E0,  a0); a1 = fmaf(q0.y, E1,  a1);
        a2 = fmaf(q0.z, E2,  a2); a3 = fmaf(q0.w, E3,  a3);
        a0 = fmaf(q1.x, E4,  a0); a1 = fmaf(q1.y, E5,  a1);
        a2 = fmaf(q1.z, E6,  a2); a3 = fmaf(q1.w, E7,  a3);
        a0 = fmaf(q2.x, E8,  a0); a1 = fmaf(q2.y, E9,  a1);
        a2 = fmaf(q2.z, E10, a2); a3 = fmaf(q2.w, E11, a3);
        a0 = fmaf(q3.x, E12, a0); a1 = fmaf(q3.y, E13, a1);
        a2 = fmaf(q3.z, E14, a2); a3 = fmaf(q3.w, E15, a3);
        float dot = (a0 + a1) + (a2 + a3);
        dot = qsum4(dot);
        float fv = __expf(e);
        if (DIR && si == nsteps - 1) fv = 1.0f;
        float wval = dot * fv;
        if ((si & 63) == 63) {
            const float m = rb[0];
            wval *= __builtin_amdgcn_rcpf(m);
            if (tid == 0) logsum += __logf(m);
        }
        if (sub == 0) wb[j] = wval;
        LDS_BARRIER();
        cur ^= 1;
    }
    const float* fin = qbuf + (cur << 6);
    float* wsb = ws + (size_t)b * WS_STRIDE;
    if (tid < TT) wsb[(DIR ? TT : 0) + tid] = fin[tid];
    if (tid == 0) wsb[DIR ? 129 : 128] = (float)((double)nsteps * LOG64) + logsum;
}

__global__ __launch_bounds__(256) void crf_fb_kernel(
    const float* __restrict__ em, const float* __restrict__ trans,
    float* __restrict__ ws)
{
    const int b   = blockIdx.x & (BB - 1);
    const int dir = blockIdx.x >> 8;
    __shared__ __align__(16) float qbuf[2 * TT];
    if (dir == 0) fb_run<0>(em, trans, ws, qbuf, b, threadIdx.x);
    else          fb_run<1>(em, trans, ws, qbuf, b, threadIdx.x);
}

__global__ __launch_bounds__(64) void crf_combine_kernel(
    const float* __restrict__ ws, float* __restrict__ outb)
{
    const int b = blockIdx.x, lane = threadIdx.x;
    const float* wsb = ws + (size_t)b * WS_STRIDE;
    float p = wsb[lane] * wsb[64 + lane];
    for (int off = 1; off < 64; off <<= 1) p += __shfl_xor(p, off);
    if (lane == 0) {
        const float logz = wsb[128] + wsb[129] + __logf(p);
        outb[b] = wsb[130] - logz;
    }
}

__global__ __launch_bounds__(256) void crf_final_kernel(
    const float* __restrict__ vals, float* __restrict__ out)
{
    const int l = threadIdx.x;
    float v = vals[l];
    for (int off = 1; off < 64; off <<= 1) v += __shfl_xor(v, off);
    __shared__ float sh[4];
    if ((l & 63) == 0) sh[l >> 6] = v;
    __syncthreads();
    if (l == 0) out[0] = -(sh[0] + sh[1] + sh[2] + sh[3]) * (1.0f / BB);
}

extern "C" void kernel_launch(void* const* d_in, const int* in_sizes, int n_in,
                              void* d_out, int out_size, void* d_ws, size_t ws_size,
                              hipStream_t stream) {
    const float*    em    = (const float*)d_in[0];
    const float*    trans = (const float*)d_in[1];
    const uint32_t* tw    = (const uint32_t*)d_in[2];
    float* ws = (float*)d_ws;

    // adaptive segment count by workspace:
    // 16 -> ~34.6MB, 8 -> ~17.8MB, 4 -> ~9.4MB, 2 -> ~5.2MB
    int sshift = 0;
    const size_t hdr = (size_t)PBASE_F * 4;
    if      (ws_size >= hdr + (((size_t)BB << 4) * 4096 * 2)) sshift = 4;
    else if (ws_size >= hdr + (((size_t)BB << 3) * 4096 * 2)) sshift = 3;
    else if (ws_size >= hdr + (((size_t)BB << 2) * 4096 * 2)) sshift = 2;
    else if (ws_size >= hdr + (((size_t)BB << 1) * 4096 * 2)) sshift = 1;

    // NO preprocessor gate here (host pass sees all builtins as absent — R11 bug)
    if (sshift) {
        const int nwaves = (BB << sshift) * 2;        // one wave per (bs, strip)
        const int nsb = nwaves / 4;                   // seg blocks
        crf_seg32_kernel<<<nsb + BB, 256, 0, stream>>>(em, trans, tw, ws, sshift, nsb);
        crf_combine2<<<BB, 64, 0, stream>>>(em, ws, sshift);
        crf_final_kernel<<<1, 256, 0, stream>>>(ws + OUTB, (float*)d_out);
        return;
    }

    // fallback: proven R7 path (tiny workspace only)
    float* outb = ws + (size_t)BB * WS_STRIDE;
    crf_fb_kernel<<<2 * BB, 256, 0, stream>>>(em, trans, ws);
    crf_gold_kernel<<<BB, 256, 0, stream>>>(em, trans, tw, ws + 130, WS_STRIDE);
    crf_combine_kernel<<<BB, 64, 0, stream>>>(ws, outb);
    crf_final_kernel<<<1, 256, 0, stream>>>(outb, (float*)d_out);
}

// Round 18
// 272.270 us; speedup vs baseline: 1.0924x; 1.0924x over previous
//
#include <hip/hip_runtime.h>
#include <cstdint>

#define BB 256
#define SS 2048
#define TT 64
#define LOG64 4.158883083359672
#define LN2   0.6931471805599453

// ---------------- ws layout (float offsets) ----------------
#define OUTB 0
#define GBASE 256
#define LBASE 512
#define LSIZE (256 * 16 * 64)           // per-column log scales (max nseg=16)
#define PBASE_F (LBASE + LSIZE)         // 262656 floats (~1.05 MB)
// P stored as bf16: (BB*nseg) matrices x 4096 entries

// ---------------- old-path (R7 fallback) constants ----------------
#define M_SPLIT 1024
#define WS_STRIDE 144

typedef float  f32x16 __attribute__((ext_vector_type(16)));
typedef float  f32x4v __attribute__((ext_vector_type(4)));
typedef unsigned int u32x4 __attribute__((ext_vector_type(4)));
typedef int    i32x2v __attribute__((ext_vector_type(2)));
typedef __bf16 bf16x8 __attribute__((ext_vector_type(8)));

__device__ __forceinline__ int ldtag(const uint32_t* tw, int i, int is64) {
    return (int)tw[i << is64];
}

__device__ __forceinline__ unsigned cvt_pk_bf16(float lo, float hi) {
    unsigned r;
    asm("v_cvt_pk_bf16_f32 %0, %1, %2" : "=v"(r) : "v"(lo), "v"(hi));
    return r;
}

// device-pass-only builtin selection; host pass sees the asm branch (never codegen'd)
__device__ __forceinline__ f32x16 mfma32(u32x4 a, u32x4 b, f32x16 c) {
#if __has_builtin(__builtin_amdgcn_mfma_f32_32x32x16_bf16)
    return __builtin_amdgcn_mfma_f32_32x32x16_bf16(
        __builtin_bit_cast(bf16x8, a), __builtin_bit_cast(bf16x8, b), c, 0, 0, 0);
#else
    f32x16 d;
    asm volatile("v_mfma_f32_32x32x16_bf16 %0, %1, %2, %3\n\ts_nop 7\n\ts_nop 7"
        : "=v"(d) : "v"(a), "v"(b), "v"(c));
    return d;
#endif
}

// two-output half-wave swap: a' = {a.lo, b.lo}, b' = {a.hi, b.hi}
__device__ __forceinline__ void plswap(unsigned& a, unsigned& b, bool hb) {
#if __has_builtin(__builtin_amdgcn_permlane32_swap)
    (void)hb;
    i32x2v r = __builtin_amdgcn_permlane32_swap((int)a, (int)b, false, false);
    a = (unsigned)r[0]; b = (unsigned)r[1];
#else
    const unsigned xa = __shfl_xor(a, 32);
    const unsigned xb = __shfl_xor(b, 32);
    const unsigned na = hb ? xb : a;
    const unsigned nb = hb ? b : xa;
    a = na; b = nb;
#endif
}

// ---------------- gold score body (used fused into seg grid + standalone) -------
__device__ __forceinline__ void gold_body(
    const float* __restrict__ em, const float* __restrict__ trans,
    const uint32_t* __restrict__ tw, float* __restrict__ gdst, int gstride,
    int b, int tid)
{
    uint32_t orv = 0;
    for (int k = 1; k < 32; k += 2) orv |= tw[k];
    const int is64 = (orv == 0) ? 1 : 0;
    const int    tbase = b * SS;
    const size_t ebase = (size_t)b * SS * TT;
    float s = 0.0f;
    for (int t = tid; t < SS; t += 256) {
        const int tg = ldtag(tw, tbase + t, is64);
        float v = em[ebase + (size_t)t * TT + tg];
        if (t > 0) {
            const int tp = ldtag(tw, tbase + t - 1, is64);
            v += trans[tp * TT + tg];
        }
        s += v;
    }
    for (int off = 1; off < 64; off <<= 1) s += __shfl_xor(s, off);
    __shared__ float sh[4];
    if ((tid & 63) == 0) sh[tid >> 6] = s;
    __syncthreads();
    if (tid == 0) gdst[b * gstride] = sh[0] + sh[1] + sh[2] + sh[3];
}

// ================= segment matrix-product kernel (32x32x16) =================
// R18 = R16 structure (the proven-best 241us: 4-dep MFMA chain, (256,4),
// unroll-8 + depth-8 prefetch + f-dbuf) with the renorm made FREE:
// fixed 2^-6 period scale folded into the f-write at unroll position 6
// (f for the p==7 step), replacing the 32-fmax+shfl+rcp+log max-renorm
// (~9 VALU cyc/step, the kernel is VALU-issue-bound: R17's +VALU regressed).
// L becomes uniform: nst*LOG64 + nouter*6*ln2. Numerics: per-8-step log
// growth ~ N(4, 8); 2^-6 = e^-4.16 centers it; 16-period random walk
// sigma ~ 11, 5-sigma tails e^+-60 << f32/bf16 range e^+-87. Exact math
// unchanged.
// Wave u = blockIdx.x*4+wv -> (bs = u>>1, strip w = u&1); private f_lds slice.
// Layouts (32x32x16 bf16): A row=l&31,k=(l>>5)*8+e ; B col=l&31,k=(l>>5)*8+e ;
// C col=l&31,row=(r&3)+8*(r>>2)+4*(l>>5)  [HW-verified; R12/13/15/16 absmax=0].
__global__ __launch_bounds__(256, 4) void crf_seg32_kernel(
    const float* __restrict__ em, const float* __restrict__ trans,
    const uint32_t* __restrict__ tw,
    float* __restrict__ ws, int sshift, int nsb)
{
    const int tid = threadIdx.x;

    if ((int)blockIdx.x >= nsb) {              // trailing blocks: gold score
        gold_body(em, trans, tw, ws + GBASE, 1, (int)blockIdx.x - nsb, tid);
        return;
    }

    const int wv = tid >> 6;                   // wave in block
    const int l  = tid & 63;
    const int c = l & 31, h = l >> 5;
    const bool hb = (h != 0);
    const int u  = blockIdx.x * 4 + wv;        // global wave id
    const int bs = u >> 1;                     // b*nseg + s
    const int w  = u & 1;                      // strip
    const int b  = bs >> sshift;
    const int s  = bs & ((1 << sshift) - 1);
    const int cn = w * 32 + c;                 // global column of this lane
    __shared__ __align__(16) float f_lds[4][2][TT];   // [wave][slot][state]
    float* fl = &f_lds[wv][0][0];

    const f32x16 ZZ = {0,0,0,0,0,0,0,0,0,0,0,0,0,0,0,0};

    // A tiles (E^T): A[m][k], m = 32mt + c, k = 16kt + 8h + e
#define MKA(NM, mt, kt) u32x4 NM; { \
        const int kb = 16*(kt) + 8*h; const int mc = 32*(mt) + c; \
        const float e0 = __expf(trans[(kb+0)*64 + mc]) * 0.015625f; \
        const float e1 = __expf(trans[(kb+1)*64 + mc]) * 0.015625f; \
        const float e2 = __expf(trans[(kb+2)*64 + mc]) * 0.015625f; \
        const float e3 = __expf(trans[(kb+3)*64 + mc]) * 0.015625f; \
        const float e4 = __expf(trans[(kb+4)*64 + mc]) * 0.015625f; \
        const float e5 = __expf(trans[(kb+5)*64 + mc]) * 0.015625f; \
        const float e6 = __expf(trans[(kb+6)*64 + mc]) * 0.015625f; \
        const float e7 = __expf(trans[(kb+7)*64 + mc]) * 0.015625f; \
        NM[0] = cvt_pk_bf16(e0, e1); NM[1] = cvt_pk_bf16(e2, e3); \
        NM[2] = cvt_pk_bf16(e4, e5); NM[3] = cvt_pk_bf16(e6, e7); }
    MKA(A00, 0, 0) MKA(A01, 0, 1) MKA(A02, 0, 2) MKA(A03, 0, 3)
    MKA(A10, 1, 0) MKA(A11, 1, 1) MKA(A12, 1, 2) MKA(A13, 1, 3)
#undef MKA

    // B init: identity strip. B[k][cn] = (k == cn), k = 16kt + 8h + e
#define MKB(NM, kt) u32x4 NM; { \
        const int kb = 16*(kt) + 8*h; \
        NM[0] = cvt_pk_bf16(kb+0==cn?1.f:0.f, kb+1==cn?1.f:0.f); \
        NM[1] = cvt_pk_bf16(kb+2==cn?1.f:0.f, kb+3==cn?1.f:0.f); \
        NM[2] = cvt_pk_bf16(kb+4==cn?1.f:0.f, kb+5==cn?1.f:0.f); \
        NM[3] = cvt_pk_bf16(kb+6==cn?1.f:0.f, kb+7==cn?1.f:0.f); }
    MKB(B0, 0) MKB(B1, 1) MKB(B2, 2) MKB(B3, 3)
#undef MKB

    const size_t ebase = (size_t)b * (SS * TT);
    const int nseg = 1 << sshift;
    const int L  = SS >> sshift;
    const int t0 = s * L + 1;
    const int t1 = (s == nseg - 1) ? (SS - 1) : (s + 1) * L;
    const int nst = t1 - t0 + 1;

    // depth-8 emission prefetch (t0+7 <= SS-1 for all segments, L>=128)
    float p0 = em[ebase + (size_t)(t0 + 0) * TT + l];
    float p1 = em[ebase + (size_t)(t0 + 1) * TT + l];
    float p2 = em[ebase + (size_t)(t0 + 2) * TT + l];
    float p3 = em[ebase + (size_t)(t0 + 3) * TT + l];
    float p4 = em[ebase + (size_t)(t0 + 4) * TT + l];
    float p5 = em[ebase + (size_t)(t0 + 5) * TT + l];
    float p6 = em[ebase + (size_t)(t0 + 6) * TT + l];
    float p7 = em[ebase + (size_t)(t0 + 7) * TT + l];

    f32x16 c0, c1;
    int si = 0;

    fl[0 * TT + l] = __expf(p0);               // f for step 0 (slot 0)

#define SC(C_, q, FV) { C_[4*(q)+0] *= FV[0]; C_[4*(q)+1] *= FV[1]; \
                        C_[4*(q)+2] *= FV[2]; C_[4*(q)+3] *= FV[3]; }
#define FEED(Bd, C_, o) { \
        unsigned T0 = cvt_pk_bf16(C_[(o)+0], C_[(o)+1]); \
        unsigned T1 = cvt_pk_bf16(C_[(o)+2], C_[(o)+3]); \
        unsigned T2 = cvt_pk_bf16(C_[(o)+4], C_[(o)+5]); \
        unsigned T3 = cvt_pk_bf16(C_[(o)+6], C_[(o)+7]); \
        plswap(T0, T2, hb); plswap(T1, T3, hb); \
        Bd[0] = T0; Bd[1] = T1; Bd[2] = T2; Bd[3] = T3; }

    // one step; KPAR = si&1 (compile-time in unrolled body).
    // FS: scale folded into the f-write (2^-6 at unroll position 6 -> the
    // period scale rides the existing row-scale of step p==7, zero extra ops).
#define STEPB(KPAR, FS) { \
        const float frn = __expf(p1) * (FS); \
        fl[(((KPAR)+1)&1) * TT + l] = frn;     /* f for step si+1, other slot */ \
        p0=p1; p1=p2; p2=p3; p3=p4; p4=p5; p5=p6; p6=p7; \
        { int tp = t0 + si + 8; if (tp > SS-1) tp = SS-1; \
          p7 = em[ebase + (size_t)tp * TT + l]; } \
        c0 = mfma32(A00, B0, ZZ);  c1 = mfma32(A10, B0, ZZ); \
        c0 = mfma32(A01, B1, c0);  c1 = mfma32(A11, B1, c1); \
        c0 = mfma32(A02, B2, c0);  c1 = mfma32(A12, B2, c1); \
        c0 = mfma32(A03, B3, c0);  c1 = mfma32(A13, B3, c1); \
        const float* flr = fl + ((KPAR)&1) * TT; \
        const f32x4v f0 = *(const f32x4v*)(flr +  0 + 4*h); \
        const f32x4v f1 = *(const f32x4v*)(flr +  8 + 4*h); \
        const f32x4v f2 = *(const f32x4v*)(flr + 16 + 4*h); \
        const f32x4v f3 = *(const f32x4v*)(flr + 24 + 4*h); \
        const f32x4v f4 = *(const f32x4v*)(flr + 32 + 4*h); \
        const f32x4v f5 = *(const f32x4v*)(flr + 40 + 4*h); \
        const f32x4v f6 = *(const f32x4v*)(flr + 48 + 4*h); \
        const f32x4v f7 = *(const f32x4v*)(flr + 56 + 4*h); \
        SC(c0,0,f0) SC(c0,1,f1) SC(c0,2,f2) SC(c0,3,f3) \
        SC(c1,0,f4) SC(c1,1,f5) SC(c1,2,f6) SC(c1,3,f7) \
        FEED(B0, c0, 0) FEED(B1, c0, 8) FEED(B2, c1, 0) FEED(B3, c1, 8) \
        ++si; }

    const int nouter = nst >> 3;
    for (int o = 0; o < nouter; ++o) {
        STEPB(0, 1.0f) STEPB(1, 1.0f) STEPB(0, 1.0f) STEPB(1, 1.0f)
        STEPB(0, 1.0f) STEPB(1, 1.0f) STEPB(0, 0.015625f) STEPB(1, 1.0f)
    }
    // tail (nst%8 < 8 steps; no period scale here — drift over <8 steps is small)
    for (; si < nst; ) {
        const int kp = si & 1;
        if (kp == 0) { STEPB(0, 1.0f) } else { STEPB(1, 1.0f) }
    }
#undef STEPB
#undef FEED
#undef SC

    // store P^T[cn][row] as bf16; rows: quad q of tile mt -> 32mt + 8q + 4h + {0..3}
    uint16_t* ptu = (uint16_t*)(ws + PBASE_F)
                  + (size_t)bs * 4096 + (size_t)cn * 64;
#define STQ(C_, q, base) { \
        *(unsigned*)(ptu + (base) + 8*(q) + 4*h)     = cvt_pk_bf16(C_[4*(q)+0], C_[4*(q)+1]); \
        *(unsigned*)(ptu + (base) + 8*(q) + 4*h + 2) = cvt_pk_bf16(C_[4*(q)+2], C_[4*(q)+3]); }
    STQ(c0,0,0) STQ(c0,1,0) STQ(c0,2,0) STQ(c0,3,0)
    STQ(c1,0,32) STQ(c1,1,32) STQ(c1,2,32) STQ(c1,3,32)
#undef STQ
    if (h == 0)
        ws[LBASE + bs * 64 + cn] =
            (float)((double)nst * LOG64 + (double)nouter * 6.0 * LN2);
}

// ================= combine: alpha <- P_s alpha over segments =================
__global__ __launch_bounds__(64) void crf_combine2(
    const float* __restrict__ em, float* __restrict__ ws, int sshift)
{
    const int b = blockIdx.x, m = threadIdx.x;
    const int nseg = 1 << sshift;
    __shared__ float xs[TT];
    float alpha = __expf(em[(size_t)b * (SS * TT) + m]);   // alpha_0
    float logA = 0.f;
    for (int s = 0; s < nseg; ++s) {
        const int seg = b * nseg + s;
        const float Li = ws[LBASE + seg * 64 + m];         // per-column scale
        float Lmax = Li;
        for (int off = 1; off < 64; off <<= 1) Lmax = fmaxf(Lmax, __shfl_xor(Lmax, off));
        xs[m] = alpha * __expf(Li - Lmax);
        const uint16_t* Pp = (const uint16_t*)(ws + PBASE_F) + (size_t)seg * 4096;
        float y = 0.f;
#pragma unroll 8
        for (int i = 0; i < TT; ++i) {
            const float pv = __uint_as_float((unsigned)Pp[i * 64 + m] << 16);
            y = fmaf(pv, xs[i], y);
        }
        logA += Lmax;
        float mx = y;
        for (int off = 1; off < 64; off <<= 1) mx = fmaxf(mx, __shfl_xor(mx, off));
        alpha = y * __builtin_amdgcn_rcpf(mx);
        logA += __logf(mx);
    }
    float ssum = alpha;
    for (int off = 1; off < 64; off <<= 1) ssum += __shfl_xor(ssum, off);
    if (m == 0)
        ws[OUTB + b] = ws[GBASE + b] - (logA + __logf(ssum));   // gold - logZ
}

// ================= standalone gold (R7 fallback path) =================
__global__ __launch_bounds__(256) void crf_gold_kernel(
    const float* __restrict__ em, const float* __restrict__ trans,
    const uint32_t* __restrict__ tw, float* __restrict__ gdst, int gstride)
{
    gold_body(em, trans, tw, gdst, gstride, blockIdx.x, threadIdx.x);
}

// ================= old path (R7, proven fallback) =================
__device__ __forceinline__ float qsum4(float v) {
    int a = __builtin_amdgcn_mov_dpp(__float_as_int(v), 0xB1, 0xF, 0xF, true);
    float v1 = v + __int_as_float(a);
    int b2 = __builtin_amdgcn_mov_dpp(__float_as_int(v1), 0x4E, 0xF, 0xF, true);
    return v1 + __int_as_float(b2);
}
#define LDS_BARRIER() asm volatile("s_waitcnt lgkmcnt(0)\n\ts_barrier" ::: "memory")

template <int DIR>
__device__ __forceinline__ void fb_run(const float* __restrict__ em,
                                       const float* __restrict__ trans,
                                       float* __restrict__ ws,
                                       float* __restrict__ qbuf,
                                       int b, int tid)
{
    const int l   = tid & 63;
    const int w   = tid >> 6;
    const int j   = (w << 4) | (l >> 2);
    const int sub = l & 3;
#define TRIDX(k) (DIR ? (j * 64 + (sub * 16 + (k))) : ((sub * 16 + (k)) * 64 + j))
#define ED(k) const float E##k = __expf(trans[TRIDX(k)]) * 0.015625f;
    ED(0) ED(1) ED(2) ED(3) ED(4) ED(5) ED(6) ED(7)
    ED(8) ED(9) ED(10) ED(11) ED(12) ED(13) ED(14) ED(15)
#undef ED
#undef TRIDX
    const size_t ebase  = (size_t)b * SS * TT;
    constexpr int nsteps = DIR ? (SS - M_SPLIT) : (M_SPLIT - 1);
    constexpr int estep  = DIR ? -TT : TT;
    constexpr int t0     = DIR ? (SS - 2) : 1;
    const float* ep = em + ebase + (size_t)t0 * TT + j;
    float p0 = ep[0];
    float p1 = ep[1 * estep];
    float p2 = ep[2 * estep];
    float p3 = ep[3 * estep];
    if (tid < TT) {
        const size_t it = DIR ? ((size_t)(SS - 1) * TT) : 0;
        qbuf[tid] = __expf(em[ebase + it + tid]);
    }
    LDS_BARRIER();
    float logsum = 0.0f;
    int cur = 0;
    for (int si = 0; si < nsteps; ++si) {
        const float e = p0;
        p0 = p1; p1 = p2; p2 = p3;
        p3 = ep[4 * estep];
        ep += estep;
        float* rb = qbuf + (cur << 6);
        float* wb = qbuf + ((cur ^ 1) << 6);
        const float4 q0 = *(const float4*)(rb + sub * 16 + 0);
        const float4 q1 = *(const float4*)(rb + sub * 16 + 4);
        const float4 q2 = *(const float4*)(rb + sub * 16 + 8);
        const float4 q3 = *(const float4*)(rb + sub * 16 + 12);
        float a0 = 0, a1 = 0, a2 = 0, a3 = 0;
        a0 = fmaf(q0.x, E0,  a0); a1 = fmaf(q0.y, E1,  a1);
        a2 = fmaf(q0.z, E2,  a2); a3 = fmaf(q0.w, E3,  a3);
        a0 = fmaf(q1.x, E4,  a0); a1 = fmaf(q1.y, E5,  a1);
        a2 = fmaf(q1.z, E6,  a2); a3 = fmaf(q1.w, E7,  a3);
        a0 = fmaf(q2.x, E8,  a0); a1 = fmaf(q2.y, E9,  a1);
        a2 = fmaf(q2.z, E10, a2); a3 = fmaf(q2.w, E11, a3);
        a0 = fmaf(q3.x, E12, a0); a1 = fmaf(q3.y, E13, a1);
        a2 = fmaf(q3.z, E14, a2); a3 = fmaf(q3.w, E15, a3);
        float dot = (a0 + a1) + (a2 + a3);
        dot = qsum4(dot);
        float fv = __expf(e);
        if (DIR && si == nsteps - 1) fv = 1.0f;
        float wval = dot * fv;
        if ((si & 63) == 63) {
            const float m = rb[0];
            wval *= __builtin_amdgcn_rcpf(m);
            if (tid == 0) logsum += __logf(m);
        }
        if (sub == 0) wb[j] = wval;
        LDS_BARRIER();
        cur ^= 1;
    }
    const float* fin = qbuf + (cur << 6);
    float* wsb = ws + (size_t)b * WS_STRIDE;
    if (tid < TT) wsb[(DIR ? TT : 0) + tid] = fin[tid];
    if (tid == 0) wsb[DIR ? 129 : 128] = (float)((double)nsteps * LOG64) + logsum;
}

__global__ __launch_bounds__(256) void crf_fb_kernel(
    const float* __restrict__ em, const float* __restrict__ trans,
    float* __restrict__ ws)
{
    const int b   = blockIdx.x & (BB - 1);
    const int dir = blockIdx.x >> 8;
    __shared__ __align__(16) float qbuf[2 * TT];
    if (dir == 0) fb_run<0>(em, trans, ws, qbuf, b, threadIdx.x);
    else          fb_run<1>(em, trans, ws, qbuf, b, threadIdx.x);
}

__global__ __launch_bounds__(64) void crf_combine_kernel(
    const float* __restrict__ ws, float* __restrict__ outb)
{
    const int b = blockIdx.x, lane = threadIdx.x;
    const float* wsb = ws + (size_t)b * WS_STRIDE;
    float p = wsb[lane] * wsb[64 + lane];
    for (int off = 1; off < 64; off <<= 1) p += __shfl_xor(p, off);
    if (lane == 0) {
        const float logz = wsb[128] + wsb[129] + __logf(p);
        outb[b] = wsb[130] - logz;
    }
}

__global__ __launch_bounds__(256) void crf_final_kernel(
    const float* __restrict__ vals, float* __restrict__ out)
{
    const int l = threadIdx.x;
    float v = vals[l];
    for (int off = 1; off < 64; off <<= 1) v += __shfl_xor(v, off);
    __shared__ float sh[4];
    if ((l & 63) == 0) sh[l >> 6] = v;
    __syncthreads();
    if (l == 0) out[0] = -(sh[0] + sh[1] + sh[2] + sh[3]) * (1.0f / BB);
}

extern "C" void kernel_launch(void* const* d_in, const int* in_sizes, int n_in,
                              void* d_out, int out_size, void* d_ws, size_t ws_size,
                              hipStream_t stream) {
    const float*    em    = (const float*)d_in[0];
    const float*    trans = (const float*)d_in[1];
    const uint32_t* tw    = (const uint32_t*)d_in[2];
    float* ws = (float*)d_ws;

    // adaptive segment count by workspace:
    // 16 -> ~34.6MB, 8 -> ~17.8MB, 4 -> ~9.4MB, 2 -> ~5.2MB
    int sshift = 0;
    const size_t hdr = (size_t)PBASE_F * 4;
    if      (ws_size >= hdr + (((size_t)BB << 4) * 4096 * 2)) sshift = 4;
    else if (ws_size >= hdr + (((size_t)BB << 3) * 4096 * 2)) sshift = 3;
    else if (ws_size >= hdr + (((size_t)BB << 2) * 4096 * 2)) sshift = 2;
    else if (ws_size >= hdr + (((size_t)BB << 1) * 4096 * 2)) sshift = 1;

    // NO preprocessor gate here (host pass sees all builtins as absent — R11 bug)
    if (sshift) {
        const int nwaves = (BB << sshift) * 2;        // one wave per (bs, strip)
        const int nsb = nwaves / 4;                   // seg blocks
        crf_seg32_kernel<<<nsb + BB, 256, 0, stream>>>(em, trans, tw, ws, sshift, nsb);
        crf_combine2<<<BB, 64, 0, stream>>>(em, ws, sshift);
        crf_final_kernel<<<1, 256, 0, stream>>>(ws + OUTB, (float*)d_out);
        return;
    }

    // fallback: proven R7 path (tiny workspace only)
    float* outb = ws + (size_t)BB * WS_STRIDE;
    crf_fb_kernel<<<2 * BB, 256, 0, stream>>>(em, trans, ws);
    crf_gold_kernel<<<BB, 256, 0, stream>>>(em, trans, tw, ws + 130, WS_STRIDE);
    crf_combine_kernel<<<BB, 64, 0, stream>>>(ws, outb);
    crf_final_kernel<<<1, 256, 0, stream>>>(outb, (float*)d_out);
}

// Round 19
// 257.390 us; speedup vs baseline: 1.1556x; 1.0578x over previous
//
#include <hip/hip_runtime.h>
#include <cstdint>

#define BB 256
#define SS 2048
#define TT 64
#define LOG64 4.158883083359672
#define LN2   0.6931471805599453

// ---------------- ws layout (float offsets) ----------------
#define OUTB 0
#define GBASE 256
#define LBASE 512
#define LSIZE (256 * 16 * 64)           // per-column log scales (max nseg=16)
#define PBASE_F (LBASE + LSIZE)         // 262656 floats (~1.05 MB)
// P stored as bf16: (BB*nseg) matrices x 4096 entries

// ---------------- old-path (R7 fallback) constants ----------------
#define M_SPLIT 1024
#define WS_STRIDE 144

typedef float  f32x16 __attribute__((ext_vector_type(16)));
typedef float  f32x4v __attribute__((ext_vector_type(4)));
typedef float  f32x2  __attribute__((ext_vector_type(2)));
typedef unsigned int u32x4 __attribute__((ext_vector_type(4)));
typedef int    i32x2v __attribute__((ext_vector_type(2)));
typedef __bf16 bf16x8 __attribute__((ext_vector_type(8)));

__device__ __forceinline__ int ldtag(const uint32_t* tw, int i, int is64) {
    return (int)tw[i << is64];
}

__device__ __forceinline__ unsigned cvt_pk_bf16(float lo, float hi) {
    unsigned r;
    asm("v_cvt_pk_bf16_f32 %0, %1, %2" : "=v"(r) : "v"(lo), "v"(hi));
    return r;
}

// device-pass-only builtin selection; host pass sees the asm branch (never codegen'd)
__device__ __forceinline__ f32x16 mfma32(u32x4 a, u32x4 b, f32x16 c) {
#if __has_builtin(__builtin_amdgcn_mfma_f32_32x32x16_bf16)
    return __builtin_amdgcn_mfma_f32_32x32x16_bf16(
        __builtin_bit_cast(bf16x8, a), __builtin_bit_cast(bf16x8, b), c, 0, 0, 0);
#else
    f32x16 d;
    asm volatile("v_mfma_f32_32x32x16_bf16 %0, %1, %2, %3\n\ts_nop 7\n\ts_nop 7"
        : "=v"(d) : "v"(a), "v"(b), "v"(c));
    return d;
#endif
}

// two-output half-wave swap: a' = {a.lo, b.lo}, b' = {a.hi, b.hi}
__device__ __forceinline__ void plswap(unsigned& a, unsigned& b, bool hb) {
#if __has_builtin(__builtin_amdgcn_permlane32_swap)
    (void)hb;
    i32x2v r = __builtin_amdgcn_permlane32_swap((int)a, (int)b, false, false);
    a = (unsigned)r[0]; b = (unsigned)r[1];
#else
    const unsigned xa = __shfl_xor(a, 32);
    const unsigned xb = __shfl_xor(b, 32);
    const unsigned na = hb ? xb : a;
    const unsigned nb = hb ? b : xa;
    a = na; b = nb;
#endif
}

// ---------------- gold score body (used fused into seg grid + standalone) -------
__device__ __forceinline__ void gold_body(
    const float* __restrict__ em, const float* __restrict__ trans,
    const uint32_t* __restrict__ tw, float* __restrict__ gdst, int gstride,
    int b, int tid)
{
    uint32_t orv = 0;
    for (int k = 1; k < 32; k += 2) orv |= tw[k];
    const int is64 = (orv == 0) ? 1 : 0;
    const int    tbase = b * SS;
    const size_t ebase = (size_t)b * SS * TT;
    float s = 0.0f;
    for (int t = tid; t < SS; t += 256) {
        const int tg = ldtag(tw, tbase + t, is64);
        float v = em[ebase + (size_t)t * TT + tg];
        if (t > 0) {
            const int tp = ldtag(tw, tbase + t - 1, is64);
            v += trans[tp * TT + tg];
        }
        s += v;
    }
    for (int off = 1; off < 64; off <<= 1) s += __shfl_xor(s, off);
    __shared__ float sh[4];
    if ((tid & 63) == 0) sh[tid >> 6] = s;
    __syncthreads();
    if (tid == 0) gdst[b * gstride] = sh[0] + sh[1] + sh[2] + sh[3];
}

// ================= segment matrix-product kernel (32x32x16) =================
// R19 = R18 (proven 234us: 4-dep MFMA chain, (256,4), unroll-8 + depth-8
// prefetch + f-dbuf + free 2^-6 period scale) with three VALU/latency cuts:
//  (a) f-scale via explicit v_pk_mul_f32 (asm, aligned f32x2 sub-pairs):
//      32 scalar muls -> 16 pk ops (R17 proved compiler doesn't auto-pack);
//  (b) clamp-free main loop: prefetch t0+si+8 <= t1 for all but the last
//      unroll group -> the min-clamp is compile-time-gated (CL flag);
//  (c) combine2 fully unrolled (64 loads in flight; 1 latency/segment).
// Wave u = blockIdx.x*4+wv -> (bs = u>>1, strip w = u&1); private f_lds slice.
// Layouts (32x32x16 bf16): A row=l&31,k=(l>>5)*8+e ; B col=l&31,k=(l>>5)*8+e ;
// C col=l&31,row=(r&3)+8*(r>>2)+4*(l>>5)  [HW-verified; R12-R18 absmax=0].
__global__ __launch_bounds__(256, 4) void crf_seg32_kernel(
    const float* __restrict__ em, const float* __restrict__ trans,
    const uint32_t* __restrict__ tw,
    float* __restrict__ ws, int sshift, int nsb)
{
    const int tid = threadIdx.x;

    if ((int)blockIdx.x >= nsb) {              // trailing blocks: gold score
        gold_body(em, trans, tw, ws + GBASE, 1, (int)blockIdx.x - nsb, tid);
        return;
    }

    const int wv = tid >> 6;                   // wave in block
    const int l  = tid & 63;
    const int c = l & 31, h = l >> 5;
    const bool hb = (h != 0);
    const int u  = blockIdx.x * 4 + wv;        // global wave id
    const int bs = u >> 1;                     // b*nseg + s
    const int w  = u & 1;                      // strip
    const int b  = bs >> sshift;
    const int s  = bs & ((1 << sshift) - 1);
    const int cn = w * 32 + c;                 // global column of this lane
    __shared__ __align__(16) float f_lds[4][2][TT];   // [wave][slot][state]
    float* fl = &f_lds[wv][0][0];

    const f32x16 ZZ = {0,0,0,0,0,0,0,0,0,0,0,0,0,0,0,0};

    // A tiles (E^T): A[m][k], m = 32mt + c, k = 16kt + 8h + e
#define MKA(NM, mt, kt) u32x4 NM; { \
        const int kb = 16*(kt) + 8*h; const int mc = 32*(mt) + c; \
        const float e0 = __expf(trans[(kb+0)*64 + mc]) * 0.015625f; \
        const float e1 = __expf(trans[(kb+1)*64 + mc]) * 0.015625f; \
        const float e2 = __expf(trans[(kb+2)*64 + mc]) * 0.015625f; \
        const float e3 = __expf(trans[(kb+3)*64 + mc]) * 0.015625f; \
        const float e4 = __expf(trans[(kb+4)*64 + mc]) * 0.015625f; \
        const float e5 = __expf(trans[(kb+5)*64 + mc]) * 0.015625f; \
        const float e6 = __expf(trans[(kb+6)*64 + mc]) * 0.015625f; \
        const float e7 = __expf(trans[(kb+7)*64 + mc]) * 0.015625f; \
        NM[0] = cvt_pk_bf16(e0, e1); NM[1] = cvt_pk_bf16(e2, e3); \
        NM[2] = cvt_pk_bf16(e4, e5); NM[3] = cvt_pk_bf16(e6, e7); }
    MKA(A00, 0, 0) MKA(A01, 0, 1) MKA(A02, 0, 2) MKA(A03, 0, 3)
    MKA(A10, 1, 0) MKA(A11, 1, 1) MKA(A12, 1, 2) MKA(A13, 1, 3)
#undef MKA

    // B init: identity strip. B[k][cn] = (k == cn), k = 16kt + 8h + e
#define MKB(NM, kt) u32x4 NM; { \
        const int kb = 16*(kt) + 8*h; \
        NM[0] = cvt_pk_bf16(kb+0==cn?1.f:0.f, kb+1==cn?1.f:0.f); \
        NM[1] = cvt_pk_bf16(kb+2==cn?1.f:0.f, kb+3==cn?1.f:0.f); \
        NM[2] = cvt_pk_bf16(kb+4==cn?1.f:0.f, kb+5==cn?1.f:0.f); \
        NM[3] = cvt_pk_bf16(kb+6==cn?1.f:0.f, kb+7==cn?1.f:0.f); }
    MKB(B0, 0) MKB(B1, 1) MKB(B2, 2) MKB(B3, 3)
#undef MKB

    const size_t ebase = (size_t)b * (SS * TT);
    const int nseg = 1 << sshift;
    const int L  = SS >> sshift;
    const int t0 = s * L + 1;
    const int t1 = (s == nseg - 1) ? (SS - 1) : (s + 1) * L;
    const int nst = t1 - t0 + 1;

    // depth-8 emission prefetch (t0+7 <= SS-1 for all segments, L>=128)
    float p0 = em[ebase + (size_t)(t0 + 0) * TT + l];
    float p1 = em[ebase + (size_t)(t0 + 1) * TT + l];
    float p2 = em[ebase + (size_t)(t0 + 2) * TT + l];
    float p3 = em[ebase + (size_t)(t0 + 3) * TT + l];
    float p4 = em[ebase + (size_t)(t0 + 4) * TT + l];
    float p5 = em[ebase + (size_t)(t0 + 5) * TT + l];
    float p6 = em[ebase + (size_t)(t0 + 6) * TT + l];
    float p7 = em[ebase + (size_t)(t0 + 7) * TT + l];

    f32x16 c0, c1;
    int si = 0;

    fl[0 * TT + l] = __expf(p0);               // f for step 0 (slot 0)

    // packed f-scale: (C[4q],C[4q+1])*=(F[0],F[1]); (C[4q+2],C[4q+3])*=(F[2],F[3])
#define SCP(C_, q, FV) { \
        f32x2 xa, xb, fa, fb; \
        xa[0]=C_[4*(q)+0]; xa[1]=C_[4*(q)+1]; \
        xb[0]=C_[4*(q)+2]; xb[1]=C_[4*(q)+3]; \
        fa[0]=FV[0]; fa[1]=FV[1]; fb[0]=FV[2]; fb[1]=FV[3]; \
        asm("v_pk_mul_f32 %0, %1, %2" : "=v"(xa) : "v"(xa), "v"(fa)); \
        asm("v_pk_mul_f32 %0, %1, %2" : "=v"(xb) : "v"(xb), "v"(fb)); \
        C_[4*(q)+0]=xa[0]; C_[4*(q)+1]=xa[1]; \
        C_[4*(q)+2]=xb[0]; C_[4*(q)+3]=xb[1]; }
#define FEED(Bd, C_, o) { \
        unsigned T0 = cvt_pk_bf16(C_[(o)+0], C_[(o)+1]); \
        unsigned T1 = cvt_pk_bf16(C_[(o)+2], C_[(o)+3]); \
        unsigned T2 = cvt_pk_bf16(C_[(o)+4], C_[(o)+5]); \
        unsigned T3 = cvt_pk_bf16(C_[(o)+6], C_[(o)+7]); \
        plswap(T0, T2, hb); plswap(T1, T3, hb); \
        Bd[0] = T0; Bd[1] = T1; Bd[2] = T2; Bd[3] = T3; }

    // one step; KPAR = si&1 (compile-time), FS = folded period scale,
    // CL = prefetch clamp needed (last unroll group / tail only).
#define STEPB(KPAR, FS, CL) { \
        const float frn = __expf(p1) * (FS); \
        fl[(((KPAR)+1)&1) * TT + l] = frn;     /* f for step si+1, other slot */ \
        p0=p1; p1=p2; p2=p3; p3=p4; p4=p5; p5=p6; p6=p7; \
        { int tp = t0 + si + 8; \
          if (CL) { if (tp > SS-1) tp = SS-1; } \
          p7 = em[ebase + (size_t)tp * TT + l]; } \
        c0 = mfma32(A00, B0, ZZ);  c1 = mfma32(A10, B0, ZZ); \
        c0 = mfma32(A01, B1, c0);  c1 = mfma32(A11, B1, c1); \
        c0 = mfma32(A02, B2, c0);  c1 = mfma32(A12, B2, c1); \
        c0 = mfma32(A03, B3, c0);  c1 = mfma32(A13, B3, c1); \
        const float* flr = fl + ((KPAR)&1) * TT; \
        const f32x4v f0 = *(const f32x4v*)(flr +  0 + 4*h); \
        const f32x4v f1 = *(const f32x4v*)(flr +  8 + 4*h); \
        const f32x4v f2 = *(const f32x4v*)(flr + 16 + 4*h); \
        const f32x4v f3 = *(const f32x4v*)(flr + 24 + 4*h); \
        const f32x4v f4 = *(const f32x4v*)(flr + 32 + 4*h); \
        const f32x4v f5 = *(const f32x4v*)(flr + 40 + 4*h); \
        const f32x4v f6 = *(const f32x4v*)(flr + 48 + 4*h); \
        const f32x4v f7 = *(const f32x4v*)(flr + 56 + 4*h); \
        SCP(c0,0,f0) SCP(c0,1,f1) SCP(c0,2,f2) SCP(c0,3,f3) \
        SCP(c1,0,f4) SCP(c1,1,f5) SCP(c1,2,f6) SCP(c1,3,f7) \
        FEED(B0, c0, 0) FEED(B1, c0, 8) FEED(B2, c1, 0) FEED(B3, c1, 8) \
        ++si; }

    const int nouter = nst >> 3;
    // main groups: prefetch stays inside segment (t0+si+8 <= t1) -> no clamp
    for (int o = 0; o < nouter - 1; ++o) {
        STEPB(0, 1.0f, false) STEPB(1, 1.0f, false)
        STEPB(0, 1.0f, false) STEPB(1, 1.0f, false)
        STEPB(0, 1.0f, false) STEPB(1, 1.0f, false)
        STEPB(0, 0.015625f, false) STEPB(1, 1.0f, false)
    }
    { // last full group: prefetch may cross t1 -> clamp
        STEPB(0, 1.0f, true) STEPB(1, 1.0f, true)
        STEPB(0, 1.0f, true) STEPB(1, 1.0f, true)
        STEPB(0, 1.0f, true) STEPB(1, 1.0f, true)
        STEPB(0, 0.015625f, true) STEPB(1, 1.0f, true)
    }
    // tail (nst%8 < 8 steps; no period scale — drift over <8 steps is small)
    for (; si < nst; ) {
        const int kp = si & 1;
        if (kp == 0) { STEPB(0, 1.0f, true) } else { STEPB(1, 1.0f, true) }
    }
#undef STEPB
#undef FEED
#undef SCP

    // store P^T[cn][row] as bf16; rows: quad q of tile mt -> 32mt + 8q + 4h + {0..3}
    uint16_t* ptu = (uint16_t*)(ws + PBASE_F)
                  + (size_t)bs * 4096 + (size_t)cn * 64;
#define STQ(C_, q, base) { \
        *(unsigned*)(ptu + (base) + 8*(q) + 4*h)     = cvt_pk_bf16(C_[4*(q)+0], C_[4*(q)+1]); \
        *(unsigned*)(ptu + (base) + 8*(q) + 4*h + 2) = cvt_pk_bf16(C_[4*(q)+2], C_[4*(q)+3]); }
    STQ(c0,0,0) STQ(c0,1,0) STQ(c0,2,0) STQ(c0,3,0)
    STQ(c1,0,32) STQ(c1,1,32) STQ(c1,2,32) STQ(c1,3,32)
#undef STQ
    if (h == 0)
        ws[LBASE + bs * 64 + cn] =
            (float)((double)nst * LOG64 + (double)(nst >> 3) * 6.0 * LN2);
}

// ================= combine: alpha <- P_s alpha over segments =================
__global__ __launch_bounds__(64) void crf_combine2(
    const float* __restrict__ em, float* __restrict__ ws, int sshift)
{
    const int b = blockIdx.x, m = threadIdx.x;
    const int nseg = 1 << sshift;
    __shared__ float xs[TT];
    float alpha = __expf(em[(size_t)b * (SS * TT) + m]);   // alpha_0
    float logA = 0.f;
    for (int s = 0; s < nseg; ++s) {
        const int seg = b * nseg + s;
        const float Li = ws[LBASE + seg * 64 + m];         // per-column scale
        float Lmax = Li;
        for (int off = 1; off < 64; off <<= 1) Lmax = fmaxf(Lmax, __shfl_xor(Lmax, off));
        xs[m] = alpha * __expf(Li - Lmax);
        const uint16_t* Pp = (const uint16_t*)(ws + PBASE_F) + (size_t)seg * 4096;
        float y = 0.f;
#pragma unroll
        for (int i = 0; i < TT; ++i) {                     // FULL unroll: 64 loads
            const float pv = __uint_as_float((unsigned)Pp[i * 64 + m] << 16);
            y = fmaf(pv, xs[i], y);                        // in flight at once
        }
        logA += Lmax;
        float mx = y;
        for (int off = 1; off < 64; off <<= 1) mx = fmaxf(mx, __shfl_xor(mx, off));
        alpha = y * __builtin_amdgcn_rcpf(mx);
        logA += __logf(mx);
    }
    float ssum = alpha;
    for (int off = 1; off < 64; off <<= 1) ssum += __shfl_xor(ssum, off);
    if (m == 0)
        ws[OUTB + b] = ws[GBASE + b] - (logA + __logf(ssum));   // gold - logZ
}

// ================= standalone gold (R7 fallback path) =================
__global__ __launch_bounds__(256) void crf_gold_kernel(
    const float* __restrict__ em, const float* __restrict__ trans,
    const uint32_t* __restrict__ tw, float* __restrict__ gdst, int gstride)
{
    gold_body(em, trans, tw, gdst, gstride, blockIdx.x, threadIdx.x);
}

// ================= old path (R7, proven fallback) =================
__device__ __forceinline__ float qsum4(float v) {
    int a = __builtin_amdgcn_mov_dpp(__float_as_int(v), 0xB1, 0xF, 0xF, true);
    float v1 = v + __int_as_float(a);
    int b2 = __builtin_amdgcn_mov_dpp(__float_as_int(v1), 0x4E, 0xF, 0xF, true);
    return v1 + __int_as_float(b2);
}
#define LDS_BARRIER() asm volatile("s_waitcnt lgkmcnt(0)\n\ts_barrier" ::: "memory")

template <int DIR>
__device__ __forceinline__ void fb_run(const float* __restrict__ em,
                                       const float* __restrict__ trans,
                                       float* __restrict__ ws,
                                       float* __restrict__ qbuf,
                                       int b, int tid)
{
    const int l   = tid & 63;
    const int w   = tid >> 6;
    const int j   = (w << 4) | (l >> 2);
    const int sub = l & 3;
#define TRIDX(k) (DIR ? (j * 64 + (sub * 16 + (k))) : ((sub * 16 + (k)) * 64 + j))
#define ED(k) const float E##k = __expf(trans[TRIDX(k)]) * 0.015625f;
    ED(0) ED(1) ED(2) ED(3) ED(4) ED(5) ED(6) ED(7)
    ED(8) ED(9) ED(10) ED(11) ED(12) ED(13) ED(14) ED(15)
#undef ED
#undef TRIDX
    const size_t ebase  = (size_t)b * SS * TT;
    constexpr int nsteps = DIR ? (SS - M_SPLIT) : (M_SPLIT - 1);
    constexpr int estep  = DIR ? -TT : TT;
    constexpr int t0     = DIR ? (SS - 2) : 1;
    const float* ep = em + ebase + (size_t)t0 * TT + j;
    float p0 = ep[0];
    float p1 = ep[1 * estep];
    float p2 = ep[2 * estep];
    float p3 = ep[3 * estep];
    if (tid < TT) {
        const size_t it = DIR ? ((size_t)(SS - 1) * TT) : 0;
        qbuf[tid] = __expf(em[ebase + it + tid]);
    }
    LDS_BARRIER();
    float logsum = 0.0f;
    int cur = 0;
    for (int si = 0; si < nsteps; ++si) {
        const float e = p0;
        p0 = p1; p1 = p2; p2 = p3;
        p3 = ep[4 * estep];
        ep += estep;
        float* rb = qbuf + (cur << 6);
        float* wb = qbuf + ((cur ^ 1) << 6);
        const float4 q0 = *(const float4*)(rb + sub * 16 + 0);
        const float4 q1 = *(const float4*)(rb + sub * 16 + 4);
        const float4 q2 = *(const float4*)(rb + sub * 16 + 8);
        const float4 q3 = *(const float4*)(rb + sub * 16 + 12);
        float a0 = 0, a1 = 0, a2 = 0, a3 = 0;
        a0 = fmaf(q0.x, E0,  a0); a1 = fmaf(q0.y, E1,  a1);
        a2 = fmaf(q0.z, E2,  a2); a3 = fmaf(q0.w, E3,  a3);
        a0 = fmaf(q1.x, E4,  a0); a1 = fmaf(q1.y, E5,  a1);
        a2 = fmaf(q1.z, E6,  a2); a3 = fmaf(q1.w, E7,  a3);
        a0 = fmaf(q2.x, E8,  a0); a1 = fmaf(q2.y, E9,  a1);
        a2 = fmaf(q2.z, E10, a2); a3 = fmaf(q2.w, E11, a3);
        a0 = fmaf(q3.x, E12, a0); a1 = fmaf(q3.y, E13, a1);
        a2 = fmaf(q3.z, E14, a2); a3 = fmaf(q3.w, E15, a3);
        float dot = (a0 + a1) + (a2 + a3);
        dot = qsum4(dot);
        float fv = __expf(e);
        if (DIR && si == nsteps - 1) fv = 1.0f;
        float wval = dot * fv;
        if ((si & 63) == 63) {
            const float m = rb[0];
            wval *= __builtin_amdgcn_rcpf(m);
            if (tid == 0) logsum += __logf(m);
        }
        if (sub == 0) wb[j] = wval;
        LDS_BARRIER();
        cur ^= 1;
    }
    const float* fin = qbuf + (cur << 6);
    float* wsb = ws + (size_t)b * WS_STRIDE;
    if (tid < TT) wsb[(DIR ? TT : 0) + tid] = fin[tid];
    if (tid == 0) wsb[DIR ? 129 : 128] = (float)((double)nsteps * LOG64) + logsum;
}

__global__ __launch_bounds__(256) void crf_fb_kernel(
    const float* __restrict__ em, const float* __restrict__ trans,
    float* __restrict__ ws)
{
    const int b   = blockIdx.x & (BB - 1);
    const int dir = blockIdx.x >> 8;
    __shared__ __align__(16) float qbuf[2 * TT];
    if (dir == 0) fb_run<0>(em, trans, ws, qbuf, b, threadIdx.x);
    else          fb_run<1>(em, trans, ws, qbuf, b, threadIdx.x);
}

__global__ __launch_bounds__(64) void crf_combine_kernel(
    const float* __restrict__ ws, float* __restrict__ outb)
{
    const int b = blockIdx.x, lane = threadIdx.x;
    const float* wsb = ws + (size_t)b * WS_STRIDE;
    float p = wsb[lane] * wsb[64 + lane];
    for (int off = 1; off < 64; off <<= 1) p += __shfl_xor(p, off);
    if (lane == 0) {
        const float logz = wsb[128] + wsb[129] + __logf(p);
        outb[b] = wsb[130] - logz;
    }
}

__global__ __launch_bounds__(256) void crf_final_kernel(
    const float* __restrict__ vals, float* __restrict__ out)
{
    const int l = threadIdx.x;
    float v = vals[l];
    for (int off = 1; off < 64; off <<= 1) v += __shfl_xor(v, off);
    __shared__ float sh[4];
    if ((l & 63) == 0) sh[l >> 6] = v;
    __syncthreads();
    if (l == 0) out[0] = -(sh[0] + sh[1] + sh[2] + sh[3]) * (1.0f / BB);
}

extern "C" void kernel_launch(void* const* d_in, const int* in_sizes, int n_in,
                              void* d_out, int out_size, void* d_ws, size_t ws_size,
                              hipStream_t stream) {
    const float*    em    = (const float*)d_in[0];
    const float*    trans = (const float*)d_in[1];
    const uint32_t* tw    = (const uint32_t*)d_in[2];
    float* ws = (float*)d_ws;

    // adaptive segment count by workspace:
    // 16 -> ~34.6MB, 8 -> ~17.8MB, 4 -> ~9.4MB, 2 -> ~5.2MB
    int sshift = 0;
    const size_t hdr = (size_t)PBASE_F * 4;
    if      (ws_size >= hdr + (((size_t)BB << 4) * 4096 * 2)) sshift = 4;
    else if (ws_size >= hdr + (((size_t)BB << 3) * 4096 * 2)) sshift = 3;
    else if (ws_size >= hdr + (((size_t)BB << 2) * 4096 * 2)) sshift = 2;
    else if (ws_size >= hdr + (((size_t)BB << 1) * 4096 * 2)) sshift = 1;

    // NO preprocessor gate here (host pass sees all builtins as absent — R11 bug)
    if (sshift) {
        const int nwaves = (BB << sshift) * 2;        // one wave per (bs, strip)
        const int nsb = nwaves / 4;                   // seg blocks
        crf_seg32_kernel<<<nsb + BB, 256, 0, stream>>>(em, trans, tw, ws, sshift, nsb);
        crf_combine2<<<BB, 64, 0, stream>>>(em, ws, sshift);
        crf_final_kernel<<<1, 256, 0, stream>>>(ws + OUTB, (float*)d_out);
        return;
    }

    // fallback: proven R7 path (tiny workspace only)
    float* outb = ws + (size_t)BB * WS_STRIDE;
    crf_fb_kernel<<<2 * BB, 256, 0, stream>>>(em, trans, ws);
    crf_gold_kernel<<<BB, 256, 0, stream>>>(em, trans, tw, ws + 130, WS_STRIDE);
    crf_combine_kernel<<<BB, 64, 0, stream>>>(ws, outb);
    crf_final_kernel<<<1, 256, 0, stream>>>(outb, (float*)d_out);
}

// Round 20
// 249.460 us; speedup vs baseline: 1.1923x; 1.0318x over previous
//
#include <hip/hip_runtime.h>
#include <cstdint>

#define BB 256
#define SS 2048
#define TT 64
#define LOG64 4.158883083359672
#define LN2   0.6931471805599453

// ---------------- ws layout (float offsets) ----------------
#define OUTB 0
#define GBASE 256
#define LBASE 512
#define LSIZE (256 * 16 * 64)           // per-column log scales (max nseg=16)
#define PBASE_F (LBASE + LSIZE)         // 262656 floats (~1.05 MB)
// P stored as bf16: (BB*nseg) matrices x 4096 entries

// ---------------- old-path (R7 fallback) constants ----------------
#define M_SPLIT 1024
#define WS_STRIDE 144

typedef float  f32x16 __attribute__((ext_vector_type(16)));
typedef float  f32x4v __attribute__((ext_vector_type(4)));
typedef unsigned int u32x4 __attribute__((ext_vector_type(4)));
typedef int    i32x2v __attribute__((ext_vector_type(2)));
typedef __bf16 bf16x8 __attribute__((ext_vector_type(8)));

__device__ __forceinline__ int ldtag(const uint32_t* tw, int i, int is64) {
    return (int)tw[i << is64];
}

__device__ __forceinline__ unsigned cvt_pk_bf16(float lo, float hi) {
    unsigned r;
    asm("v_cvt_pk_bf16_f32 %0, %1, %2" : "=v"(r) : "v"(lo), "v"(hi));
    return r;
}

// device-pass-only builtin selection; host pass sees the asm branch (never codegen'd)
__device__ __forceinline__ f32x16 mfma32(u32x4 a, u32x4 b, f32x16 c) {
#if __has_builtin(__builtin_amdgcn_mfma_f32_32x32x16_bf16)
    return __builtin_amdgcn_mfma_f32_32x32x16_bf16(
        __builtin_bit_cast(bf16x8, a), __builtin_bit_cast(bf16x8, b), c, 0, 0, 0);
#else
    f32x16 d;
    asm volatile("v_mfma_f32_32x32x16_bf16 %0, %1, %2, %3\n\ts_nop 7\n\ts_nop 7"
        : "=v"(d) : "v"(a), "v"(b), "v"(c));
    return d;
#endif
}

// two-output half-wave swap: a' = {a.lo, b.lo}, b' = {a.hi, b.hi}
__device__ __forceinline__ void plswap(unsigned& a, unsigned& b, bool hb) {
#if __has_builtin(__builtin_amdgcn_permlane32_swap)
    (void)hb;
    i32x2v r = __builtin_amdgcn_permlane32_swap((int)a, (int)b, false, false);
    a = (unsigned)r[0]; b = (unsigned)r[1];
#else
    const unsigned xa = __shfl_xor(a, 32);
    const unsigned xb = __shfl_xor(b, 32);
    const unsigned na = hb ? xb : a;
    const unsigned nb = hb ? b : xa;
    a = na; b = nb;
#endif
}

// ---------------- gold score body (used fused into seg grid + standalone) -------
__device__ __forceinline__ void gold_body(
    const float* __restrict__ em, const float* __restrict__ trans,
    const uint32_t* __restrict__ tw, float* __restrict__ gdst, int gstride,
    int b, int tid)
{
    uint32_t orv = 0;
    for (int k = 1; k < 32; k += 2) orv |= tw[k];
    const int is64 = (orv == 0) ? 1 : 0;
    const int    tbase = b * SS;
    const size_t ebase = (size_t)b * SS * TT;
    float s = 0.0f;
    for (int t = tid; t < SS; t += 256) {
        const int tg = ldtag(tw, tbase + t, is64);
        float v = em[ebase + (size_t)t * TT + tg];
        if (t > 0) {
            const int tp = ldtag(tw, tbase + t - 1, is64);
            v += trans[tp * TT + tg];
        }
        s += v;
    }
    for (int off = 1; off < 64; off <<= 1) s += __shfl_xor(s, off);
    __shared__ float sh[4];
    if ((tid & 63) == 0) sh[tid >> 6] = s;
    __syncthreads();
    if (tid == 0) gdst[b * gstride] = sh[0] + sh[1] + sh[2] + sh[3];
}

// ================= segment matrix-product kernel (32x32x16) =================
// R20 = best proven combination:
//  - R18 core (234us seg): 4-dep MFMA chain, (256,4), unroll-8 + depth-8
//    prefetch + f-dbuf + free 2^-6 period scale, SCALAR f-scale muls
//    (R19's asm v_pk_mul copies perturbed regalloc -> 30MB scratch stores,
//     seg 234->247; reverted)
//  - R19's clamp-free main loop (compile-time CL flag)
//  - R19's fully-unrolled combine2 (non-seg overhead 38us -> ~10us)
// Wave u = blockIdx.x*4+wv -> (bs = u>>1, strip w = u&1); private f_lds slice.
// Layouts (32x32x16 bf16): A row=l&31,k=(l>>5)*8+e ; B col=l&31,k=(l>>5)*8+e ;
// C col=l&31,row=(r&3)+8*(r>>2)+4*(l>>5)  [HW-verified; R12-R19 absmax=0].
__global__ __launch_bounds__(256, 4) void crf_seg32_kernel(
    const float* __restrict__ em, const float* __restrict__ trans,
    const uint32_t* __restrict__ tw,
    float* __restrict__ ws, int sshift, int nsb)
{
    const int tid = threadIdx.x;

    if ((int)blockIdx.x >= nsb) {              // trailing blocks: gold score
        gold_body(em, trans, tw, ws + GBASE, 1, (int)blockIdx.x - nsb, tid);
        return;
    }

    const int wv = tid >> 6;                   // wave in block
    const int l  = tid & 63;
    const int c = l & 31, h = l >> 5;
    const bool hb = (h != 0);
    const int u  = blockIdx.x * 4 + wv;        // global wave id
    const int bs = u >> 1;                     // b*nseg + s
    const int w  = u & 1;                      // strip
    const int b  = bs >> sshift;
    const int s  = bs & ((1 << sshift) - 1);
    const int cn = w * 32 + c;                 // global column of this lane
    __shared__ __align__(16) float f_lds[4][2][TT];   // [wave][slot][state]
    float* fl = &f_lds[wv][0][0];

    const f32x16 ZZ = {0,0,0,0,0,0,0,0,0,0,0,0,0,0,0,0};

    // A tiles (E^T): A[m][k], m = 32mt + c, k = 16kt + 8h + e
#define MKA(NM, mt, kt) u32x4 NM; { \
        const int kb = 16*(kt) + 8*h; const int mc = 32*(mt) + c; \
        const float e0 = __expf(trans[(kb+0)*64 + mc]) * 0.015625f; \
        const float e1 = __expf(trans[(kb+1)*64 + mc]) * 0.015625f; \
        const float e2 = __expf(trans[(kb+2)*64 + mc]) * 0.015625f; \
        const float e3 = __expf(trans[(kb+3)*64 + mc]) * 0.015625f; \
        const float e4 = __expf(trans[(kb+4)*64 + mc]) * 0.015625f; \
        const float e5 = __expf(trans[(kb+5)*64 + mc]) * 0.015625f; \
        const float e6 = __expf(trans[(kb+6)*64 + mc]) * 0.015625f; \
        const float e7 = __expf(trans[(kb+7)*64 + mc]) * 0.015625f; \
        NM[0] = cvt_pk_bf16(e0, e1); NM[1] = cvt_pk_bf16(e2, e3); \
        NM[2] = cvt_pk_bf16(e4, e5); NM[3] = cvt_pk_bf16(e6, e7); }
    MKA(A00, 0, 0) MKA(A01, 0, 1) MKA(A02, 0, 2) MKA(A03, 0, 3)
    MKA(A10, 1, 0) MKA(A11, 1, 1) MKA(A12, 1, 2) MKA(A13, 1, 3)
#undef MKA

    // B init: identity strip. B[k][cn] = (k == cn), k = 16kt + 8h + e
#define MKB(NM, kt) u32x4 NM; { \
        const int kb = 16*(kt) + 8*h; \
        NM[0] = cvt_pk_bf16(kb+0==cn?1.f:0.f, kb+1==cn?1.f:0.f); \
        NM[1] = cvt_pk_bf16(kb+2==cn?1.f:0.f, kb+3==cn?1.f:0.f); \
        NM[2] = cvt_pk_bf16(kb+4==cn?1.f:0.f, kb+5==cn?1.f:0.f); \
        NM[3] = cvt_pk_bf16(kb+6==cn?1.f:0.f, kb+7==cn?1.f:0.f); }
    MKB(B0, 0) MKB(B1, 1) MKB(B2, 2) MKB(B3, 3)
#undef MKB

    const size_t ebase = (size_t)b * (SS * TT);
    const int nseg = 1 << sshift;
    const int L  = SS >> sshift;
    const int t0 = s * L + 1;
    const int t1 = (s == nseg - 1) ? (SS - 1) : (s + 1) * L;
    const int nst = t1 - t0 + 1;

    // depth-8 emission prefetch (t0+7 <= SS-1 for all segments, L>=128)
    float p0 = em[ebase + (size_t)(t0 + 0) * TT + l];
    float p1 = em[ebase + (size_t)(t0 + 1) * TT + l];
    float p2 = em[ebase + (size_t)(t0 + 2) * TT + l];
    float p3 = em[ebase + (size_t)(t0 + 3) * TT + l];
    float p4 = em[ebase + (size_t)(t0 + 4) * TT + l];
    float p5 = em[ebase + (size_t)(t0 + 5) * TT + l];
    float p6 = em[ebase + (size_t)(t0 + 6) * TT + l];
    float p7 = em[ebase + (size_t)(t0 + 7) * TT + l];

    f32x16 c0, c1;
    int si = 0;

    fl[0 * TT + l] = __expf(p0);               // f for step 0 (slot 0)

#define SC(C_, q, FV) { C_[4*(q)+0] *= FV[0]; C_[4*(q)+1] *= FV[1]; \
                        C_[4*(q)+2] *= FV[2]; C_[4*(q)+3] *= FV[3]; }
#define FEED(Bd, C_, o) { \
        unsigned T0 = cvt_pk_bf16(C_[(o)+0], C_[(o)+1]); \
        unsigned T1 = cvt_pk_bf16(C_[(o)+2], C_[(o)+3]); \
        unsigned T2 = cvt_pk_bf16(C_[(o)+4], C_[(o)+5]); \
        unsigned T3 = cvt_pk_bf16(C_[(o)+6], C_[(o)+7]); \
        plswap(T0, T2, hb); plswap(T1, T3, hb); \
        Bd[0] = T0; Bd[1] = T1; Bd[2] = T2; Bd[3] = T3; }

    // one step; KPAR = si&1 (compile-time), FS = folded period scale,
    // CL = prefetch clamp needed (last unroll group / tail only).
#define STEPB(KPAR, FS, CL) { \
        const float frn = __expf(p1) * (FS); \
        fl[(((KPAR)+1)&1) * TT + l] = frn;     /* f for step si+1, other slot */ \
        p0=p1; p1=p2; p2=p3; p3=p4; p4=p5; p5=p6; p6=p7; \
        { int tp = t0 + si + 8; \
          if (CL) { if (tp > SS-1) tp = SS-1; } \
          p7 = em[ebase + (size_t)tp * TT + l]; } \
        c0 = mfma32(A00, B0, ZZ);  c1 = mfma32(A10, B0, ZZ); \
        c0 = mfma32(A01, B1, c0);  c1 = mfma32(A11, B1, c1); \
        c0 = mfma32(A02, B2, c0);  c1 = mfma32(A12, B2, c1); \
        c0 = mfma32(A03, B3, c0);  c1 = mfma32(A13, B3, c1); \
        const float* flr = fl + ((KPAR)&1) * TT; \
        const f32x4v f0 = *(const f32x4v*)(flr +  0 + 4*h); \
        const f32x4v f1 = *(const f32x4v*)(flr +  8 + 4*h); \
        const f32x4v f2 = *(const f32x4v*)(flr + 16 + 4*h); \
        const f32x4v f3 = *(const f32x4v*)(flr + 24 + 4*h); \
        const f32x4v f4 = *(const f32x4v*)(flr + 32 + 4*h); \
        const f32x4v f5 = *(const f32x4v*)(flr + 40 + 4*h); \
        const f32x4v f6 = *(const f32x4v*)(flr + 48 + 4*h); \
        const f32x4v f7 = *(const f32x4v*)(flr + 56 + 4*h); \
        SC(c0,0,f0) SC(c0,1,f1) SC(c0,2,f2) SC(c0,3,f3) \
        SC(c1,0,f4) SC(c1,1,f5) SC(c1,2,f6) SC(c1,3,f7) \
        FEED(B0, c0, 0) FEED(B1, c0, 8) FEED(B2, c1, 0) FEED(B3, c1, 8) \
        ++si; }

    const int nouter = nst >> 3;
    // main groups: prefetch stays inside segment (t0+si+8 <= t1) -> no clamp
    for (int o = 0; o < nouter - 1; ++o) {
        STEPB(0, 1.0f, false) STEPB(1, 1.0f, false)
        STEPB(0, 1.0f, false) STEPB(1, 1.0f, false)
        STEPB(0, 1.0f, false) STEPB(1, 1.0f, false)
        STEPB(0, 0.015625f, false) STEPB(1, 1.0f, false)
    }
    { // last full group: prefetch may cross t1 -> clamp
        STEPB(0, 1.0f, true) STEPB(1, 1.0f, true)
        STEPB(0, 1.0f, true) STEPB(1, 1.0f, true)
        STEPB(0, 1.0f, true) STEPB(1, 1.0f, true)
        STEPB(0, 0.015625f, true) STEPB(1, 1.0f, true)
    }
    // tail (nst%8 < 8 steps; no period scale — drift over <8 steps is small)
    for (; si < nst; ) {
        const int kp = si & 1;
        if (kp == 0) { STEPB(0, 1.0f, true) } else { STEPB(1, 1.0f, true) }
    }
#undef STEPB
#undef FEED
#undef SC

    // store P^T[cn][row] as bf16; rows: quad q of tile mt -> 32mt + 8q + 4h + {0..3}
    uint16_t* ptu = (uint16_t*)(ws + PBASE_F)
                  + (size_t)bs * 4096 + (size_t)cn * 64;
#define STQ(C_, q, base) { \
        *(unsigned*)(ptu + (base) + 8*(q) + 4*h)     = cvt_pk_bf16(C_[4*(q)+0], C_[4*(q)+1]); \
        *(unsigned*)(ptu + (base) + 8*(q) + 4*h + 2) = cvt_pk_bf16(C_[4*(q)+2], C_[4*(q)+3]); }
    STQ(c0,0,0) STQ(c0,1,0) STQ(c0,2,0) STQ(c0,3,0)
    STQ(c1,0,32) STQ(c1,1,32) STQ(c1,2,32) STQ(c1,3,32)
#undef STQ
    if (h == 0)
        ws[LBASE + bs * 64 + cn] =
            (float)((double)nst * LOG64 + (double)(nst >> 3) * 6.0 * LN2);
}

// ================= combine: alpha <- P_s alpha over segments =================
__global__ __launch_bounds__(64) void crf_combine2(
    const float* __restrict__ em, float* __restrict__ ws, int sshift)
{
    const int b = blockIdx.x, m = threadIdx.x;
    const int nseg = 1 << sshift;
    __shared__ float xs[TT];
    float alpha = __expf(em[(size_t)b * (SS * TT) + m]);   // alpha_0
    float logA = 0.f;
    for (int s = 0; s < nseg; ++s) {
        const int seg = b * nseg + s;
        const float Li = ws[LBASE + seg * 64 + m];         // per-column scale
        float Lmax = Li;
        for (int off = 1; off < 64; off <<= 1) Lmax = fmaxf(Lmax, __shfl_xor(Lmax, off));
        xs[m] = alpha * __expf(Li - Lmax);
        const uint16_t* Pp = (const uint16_t*)(ws + PBASE_F) + (size_t)seg * 4096;
        float y = 0.f;
#pragma unroll
        for (int i = 0; i < TT; ++i) {                     // FULL unroll: 64 loads
            const float pv = __uint_as_float((unsigned)Pp[i * 64 + m] << 16);
            y = fmaf(pv, xs[i], y);                        // in flight at once
        }
        logA += Lmax;
        float mx = y;
        for (int off = 1; off < 64; off <<= 1) mx = fmaxf(mx, __shfl_xor(mx, off));
        alpha = y * __builtin_amdgcn_rcpf(mx);
        logA += __logf(mx);
    }
    float ssum = alpha;
    for (int off = 1; off < 64; off <<= 1) ssum += __shfl_xor(ssum, off);
    if (m == 0)
        ws[OUTB + b] = ws[GBASE + b] - (logA + __logf(ssum));   // gold - logZ
}

// ================= standalone gold (R7 fallback path) =================
__global__ __launch_bounds__(256) void crf_gold_kernel(
    const float* __restrict__ em, const float* __restrict__ trans,
    const uint32_t* __restrict__ tw, float* __restrict__ gdst, int gstride)
{
    gold_body(em, trans, tw, gdst, gstride, blockIdx.x, threadIdx.x);
}

// ================= old path (R7, proven fallback) =================
__device__ __forceinline__ float qsum4(float v) {
    int a = __builtin_amdgcn_mov_dpp(__float_as_int(v), 0xB1, 0xF, 0xF, true);
    float v1 = v + __int_as_float(a);
    int b2 = __builtin_amdgcn_mov_dpp(__float_as_int(v1), 0x4E, 0xF, 0xF, true);
    return v1 + __int_as_float(b2);
}
#define LDS_BARRIER() asm volatile("s_waitcnt lgkmcnt(0)\n\ts_barrier" ::: "memory")

template <int DIR>
__device__ __forceinline__ void fb_run(const float* __restrict__ em,
                                       const float* __restrict__ trans,
                                       float* __restrict__ ws,
                                       float* __restrict__ qbuf,
                                       int b, int tid)
{
    const int l   = tid & 63;
    const int w   = tid >> 6;
    const int j   = (w << 4) | (l >> 2);
    const int sub = l & 3;
#define TRIDX(k) (DIR ? (j * 64 + (sub * 16 + (k))) : ((sub * 16 + (k)) * 64 + j))
#define ED(k) const float E##k = __expf(trans[TRIDX(k)]) * 0.015625f;
    ED(0) ED(1) ED(2) ED(3) ED(4) ED(5) ED(6) ED(7)
    ED(8) ED(9) ED(10) ED(11) ED(12) ED(13) ED(14) ED(15)
#undef ED
#undef TRIDX
    const size_t ebase  = (size_t)b * SS * TT;
    constexpr int nsteps = DIR ? (SS - M_SPLIT) : (M_SPLIT - 1);
    constexpr int estep  = DIR ? -TT : TT;
    constexpr int t0     = DIR ? (SS - 2) : 1;
    const float* ep = em + ebase + (size_t)t0 * TT + j;
    float p0 = ep[0];
    float p1 = ep[1 * estep];
    float p2 = ep[2 * estep];
    float p3 = ep[3 * estep];
    if (tid < TT) {
        const size_t it = DIR ? ((size_t)(SS - 1) * TT) : 0;
        qbuf[tid] = __expf(em[ebase + it + tid]);
    }
    LDS_BARRIER();
    float logsum = 0.0f;
    int cur = 0;
    for (int si = 0; si < nsteps; ++si) {
        const float e = p0;
        p0 = p1; p1 = p2; p2 = p3;
        p3 = ep[4 * estep];
        ep += estep;
        float* rb = qbuf + (cur << 6);
        float* wb = qbuf + ((cur ^ 1) << 6);
        const float4 q0 = *(const float4*)(rb + sub * 16 + 0);
        const float4 q1 = *(const float4*)(rb + sub * 16 + 4);
        const float4 q2 = *(const float4*)(rb + sub * 16 + 8);
        const float4 q3 = *(const float4*)(rb + sub * 16 + 12);
        float a0 = 0, a1 = 0, a2 = 0, a3 = 0;
        a0 = fmaf(q0.x, E0,  a0); a1 = fmaf(q0.y, E1,  a1);
        a2 = fmaf(q0.z, E2,  a2); a3 = fmaf(q0.w, E3,  a3);
        a0 = fmaf(q1.x, E4,  a0); a1 = fmaf(q1.y, E5,  a1);
        a2 = fmaf(q1.z, E6,  a2); a3 = fmaf(q1.w, E7,  a3);
        a0 = fmaf(q2.x, E8,  a0); a1 = fmaf(q2.y, E9,  a1);
        a2 = fmaf(q2.z, E10, a2); a3 = fmaf(q2.w, E11, a3);
        a0 = fmaf(q3.x, E12, a0); a1 = fmaf(q3.y, E13, a1);
        a2 = fmaf(q3.z, E14, a2); a3 = fmaf(q3.w, E15, a3);
        float dot = (a0 + a1) + (a2 + a3);
        dot = qsum4(dot);
        float fv = __expf(e);
        if (DIR && si == nsteps - 1) fv = 1.0f;
        float wval = dot * fv;
        if ((si & 63) == 63) {
            const float m = rb[0];
            wval *= __builtin_amdgcn_rcpf(m);
            if (tid == 0) logsum += __logf(m);
        }
        if (sub == 0) wb[j] = wval;
        LDS_BARRIER();
        cur ^= 1;
    }
    const float* fin = qbuf + (cur << 6);
    float* wsb = ws + (size_t)b * WS_STRIDE;
    if (tid < TT) wsb[(DIR ? TT : 0) + tid] = fin[tid];
    if (tid == 0) wsb[DIR ? 129 : 128] = (float)((double)nsteps * LOG64) + logsum;
}

__global__ __launch_bounds__(256) void crf_fb_kernel(
    const float* __restrict__ em, const float* __restrict__ trans,
    float* __restrict__ ws)
{
    const int b   = blockIdx.x & (BB - 1);
    const int dir = blockIdx.x >> 8;
    __shared__ __align__(16) float qbuf[2 * TT];
    if (dir == 0) fb_run<0>(em, trans, ws, qbuf, b, threadIdx.x);
    else          fb_run<1>(em, trans, ws, qbuf, b, threadIdx.x);
}

__global__ __launch_bounds__(64) void crf_combine_kernel(
    const float* __restrict__ ws, float* __restrict__ outb)
{
    const int b = blockIdx.x, lane = threadIdx.x;
    const float* wsb = ws + (size_t)b * WS_STRIDE;
    float p = wsb[lane] * wsb[64 + lane];
    for (int off = 1; off < 64; off <<= 1) p += __shfl_xor(p, off);
    if (lane == 0) {
        const float logz = wsb[128] + wsb[129] + __logf(p);
        outb[b] = wsb[130] - logz;
    }
}

__global__ __launch_bounds__(256) void crf_final_kernel(
    const float* __restrict__ vals, float* __restrict__ out)
{
    const int l = threadIdx.x;
    float v = vals[l];
    for (int off = 1; off < 64; off <<= 1) v += __shfl_xor(v, off);
    __shared__ float sh[4];
    if ((l & 63) == 0) sh[l >> 6] = v;
    __syncthreads();
    if (l == 0) out[0] = -(sh[0] + sh[1] + sh[2] + sh[3]) * (1.0f / BB);
}

extern "C" void kernel_launch(void* const* d_in, const int* in_sizes, int n_in,
                              void* d_out, int out_size, void* d_ws, size_t ws_size,
                              hipStream_t stream) {
    const float*    em    = (const float*)d_in[0];
    const float*    trans = (const float*)d_in[1];
    const uint32_t* tw    = (const uint32_t*)d_in[2];
    float* ws = (float*)d_ws;

    // adaptive segment count by workspace:
    // 16 -> ~34.6MB, 8 -> ~17.8MB, 4 -> ~9.4MB, 2 -> ~5.2MB
    int sshift = 0;
    const size_t hdr = (size_t)PBASE_F * 4;
    if      (ws_size >= hdr + (((size_t)BB << 4) * 4096 * 2)) sshift = 4;
    else if (ws_size >= hdr + (((size_t)BB << 3) * 4096 * 2)) sshift = 3;
    else if (ws_size >= hdr + (((size_t)BB << 2) * 4096 * 2)) sshift = 2;
    else if (ws_size >= hdr + (((size_t)BB << 1) * 4096 * 2)) sshift = 1;

    // NO preprocessor gate here (host pass sees all builtins as absent — R11 bug)
    if (sshift) {
        const int nwaves = (BB << sshift) * 2;        // one wave per (bs, strip)
        const int nsb = nwaves / 4;                   // seg blocks
        crf_seg32_kernel<<<nsb + BB, 256, 0, stream>>>(em, trans, tw, ws, sshift, nsb);
        crf_combine2<<<BB, 64, 0, stream>>>(em, ws, sshift);
        crf_final_kernel<<<1, 256, 0, stream>>>(ws + OUTB, (float*)d_out);
        return;
    }

    // fallback: proven R7 path (tiny workspace only)
    float* outb = ws + (size_t)BB * WS_STRIDE;
    crf_fb_kernel<<<2 * BB, 256, 0, stream>>>(em, trans, ws);
    crf_gold_kernel<<<BB, 256, 0, stream>>>(em, trans, tw, ws + 130, WS_STRIDE);
    crf_combine_kernel<<<BB, 64, 0, stream>>>(ws, outb);
    crf_final_kernel<<<1, 256, 0, stream>>>(outb, (float*)d_out);
}